// Round 1
// baseline (1099.572 us; speedup 1.0000x reference)
//
#include <hip/hip_runtime.h>
#include <math.h>

#define NB 64       // batch
#define NS 512      // seq len
#define ND 512      // input dim
#define NH 512      // hidden
// F = 8 factor rows, G = 256

__device__ __forceinline__ float dot4(float4 a, float4 b) {
    return a.x * b.x + a.y * b.y + a.z * b.z + a.w * b.w;
}

__device__ __forceinline__ float wave_reduce64(float v) {
#pragma unroll
    for (int off = 32; off > 0; off >>= 1) v += __shfl_xor(v, off, 64);
    return v;
}

__device__ __forceinline__ float sigm(float x) {
    return 1.0f / (1.0f + __expf(-x));
}

__device__ __forceinline__ float tanh_fast(float x) {
    // safe for large |x|: e -> inf gives r -> 1
    float ax = fabsf(x);
    float e = __expf(2.0f * ax);
    float r = 1.0f - 2.0f / (e + 1.0f);
    return copysignf(r, x);
}

// ---------------------------------------------------------------------------
// Kernel A: P[bt][0..7] = W12 @ x_bt, P[bt][8..15] = dW12 @ x_bt
// one wave per (b,t) row
// ---------------------------------------------------------------------------
__global__ __launch_bounds__(64) void precomp_kernel(
    const float* __restrict__ x, const float* __restrict__ W12,
    const float* __restrict__ dW12, float* __restrict__ P) {
    int bt = blockIdx.x;
    int l = threadIdx.x;  // 0..63
    const float4* xr = (const float4*)(x + (size_t)bt * ND);
    float4 xv0 = xr[l];        // k = 4l..4l+3
    float4 xv1 = xr[64 + l];   // k = 256+4l..

    float acc[16];
#pragma unroll
    for (int f = 0; f < 8; ++f) {
        const float4* w = (const float4*)(W12 + f * ND);
        acc[f] = dot4(w[l], xv0) + dot4(w[64 + l], xv1);
        const float4* dw = (const float4*)(dW12 + f * ND);
        acc[8 + f] = dot4(dw[l], xv0) + dot4(dw[64 + l], xv1);
    }
#pragma unroll
    for (int f = 0; f < 16; ++f) acc[f] = wave_reduce64(acc[f]);

    if (l == 0) {
        float4* o = (float4*)(P + (size_t)bt * 16);
        o[0] = make_float4(acc[0], acc[1], acc[2], acc[3]);
        o[1] = make_float4(acc[4], acc[5], acc[6], acc[7]);
        o[2] = make_float4(acc[8], acc[9], acc[10], acc[11]);
        o[3] = make_float4(acc[12], acc[13], acc[14], acc[15]);
    }
}

// ---------------------------------------------------------------------------
// Kernel B: persistent recurrence — one workgroup per batch element.
// 512 threads = 8 waves. Wave w owns factor row f=w for all dot products.
// Thread h owns hidden index h: all 4 gate rows, c1/c2 in registers.
// ---------------------------------------------------------------------------
__global__ __launch_bounds__(512) void lstm_kernel(
    const float* __restrict__ P, const float* __restrict__ h0,
    const float* __restrict__ c0,
    const float* __restrict__ W11, const float* __restrict__ U11,
    const float* __restrict__ dW11, const float* __restrict__ dU11,
    const float* __restrict__ U12, const float* __restrict__ dU12,
    const float* __restrict__ b11, const float* __restrict__ b12,
    const float* __restrict__ W21, const float* __restrict__ U21,
    const float* __restrict__ dW21, const float* __restrict__ dU21,
    const float* __restrict__ W22, const float* __restrict__ dW22,
    const float* __restrict__ U22, const float* __restrict__ dU22,
    const float* __restrict__ b21, const float* __restrict__ b22,
    float* __restrict__ out) {
    int b = blockIdx.x;
    int tid = threadIdx.x;       // 0..511 == hidden index h
    int wv = tid >> 6;           // wave -> factor row f
    int l = tid & 63;            // lane

    __shared__ float h1s[NH];
    __shared__ float h2s[NH];
    __shared__ float Mb[48];  // [0..7]=L1 M3, [8..15]=L1 M4,
                              // [16..23]=L2 M1, [24..31]=M2, [32..39]=M3, [40..47]=M4

    // --- per-wave dot-product weights into registers (fixed for all steps) ---
    const float4* pU12 = (const float4*)(U12 + wv * NH);
    const float4* pdU12 = (const float4*)(dU12 + wv * NH);
    const float4* pW22 = (const float4*)(W22 + wv * NH);
    const float4* pdW22 = (const float4*)(dW22 + wv * NH);
    const float4* pU22 = (const float4*)(U22 + wv * NH);
    const float4* pdU22 = (const float4*)(dU22 + wv * NH);
    float4 u12a = pU12[l], u12b = pU12[64 + l];
    float4 du12a = pdU12[l], du12b = pdU12[64 + l];
    float4 w22a = pW22[l], w22b = pW22[64 + l];
    float4 dw22a = pdW22[l], dw22b = pdW22[64 + l];
    float4 u22a = pU22[l], u22b = pU22[64 + l];
    float4 du22a = pdU22[l], du22b = pdU22[64 + l];

    // --- per-thread gate coefficients (fixed for all steps) ---
    float cW1[4], cdW1[4], cU1[4], cdU1[4], bb1[4];
    float cW2[4], cdW2[4], cU2[4], cdU2[4], bb2[4];
#pragma unroll
    for (int q = 0; q < 4; ++q) {
        int idx = q * 64 + (tid >> 3);
        cW1[q] = W11[idx]; cdW1[q] = dW11[idx];
        cU1[q] = U11[idx]; cdU1[q] = dU11[idx];
        bb1[q] = b11[q * NH + tid] + b12[q * NH + tid];
        cW2[q] = W21[idx]; cdW2[q] = dW21[idx];
        cU2[q] = U21[idx]; cdU2[q] = dU21[idx];
        bb2[q] = b21[q * NH + tid] + b22[q * NH + tid];
    }

    // --- initial state ---
    float c1 = c0[(size_t)b * NH + tid];
    float c2 = c0[(size_t)NB * NH + (size_t)b * NH + tid];
    h1s[tid] = h0[(size_t)b * NH + tid];
    h2s[tid] = h0[(size_t)NB * NH + (size_t)b * NH + tid];
    float h1v = h1s[tid], h2v = h2s[tid];
    __syncthreads();

    const float* Pb = P + (size_t)b * NS * 16;
    float* outb = out + (size_t)b * NS * NH;
    int f8 = tid & 7;

    for (int t = 0; t < NS; ++t) {
        // prefetch layer-1 input contributions (global, L2-resident)
        float p1 = Pb[t * 16 + f8];
        float p2 = Pb[t * 16 + 8 + f8];

        // ---- phase 1: layer-1 recurrent dots  M3=U12@h1, M4=dU12@h1 ----
        float4 hv0 = *(const float4*)&h1s[4 * l];
        float4 hv1 = *(const float4*)&h1s[256 + 4 * l];
        float a3 = dot4(u12a, hv0) + dot4(u12b, hv1);
        float a4 = dot4(du12a, hv0) + dot4(du12b, hv1);
        a3 = wave_reduce64(a3);
        a4 = wave_reduce64(a4);
        if (l == 0) { Mb[wv] = a3; Mb[8 + wv] = a4; }
        __syncthreads();

        // ---- phase 2: layer-1 gates ----
        {
            float m3 = Mb[f8], m4 = Mb[8 + f8];
            float g0 = cW1[0] * p1 + cdW1[0] * p2 + cU1[0] * m3 + cdU1[0] * m4 + bb1[0];
            float g1 = cW1[1] * p1 + cdW1[1] * p2 + cU1[1] * m3 + cdU1[1] * m4 + bb1[1];
            float g2 = cW1[2] * p1 + cdW1[2] * p2 + cU1[2] * m3 + cdU1[2] * m4 + bb1[2];
            float g3 = cW1[3] * p1 + cdW1[3] * p2 + cU1[3] * m3 + cdU1[3] * m4 + bb1[3];
            float ig = sigm(g0), fg = sigm(g1), gg = tanh_fast(g2), og = sigm(g3);
            c1 = fg * c1 + ig * gg;
            h1v = og * tanh_fast(c1);
            h1s[tid] = h1v;
        }
        __syncthreads();

        // ---- phase 3: layer-2 dots  M1=W22@h1n, M2=dW22@h1n, M3=U22@h2, M4=dU22@h2 ----
        {
            float4 x0 = *(const float4*)&h1s[4 * l];
            float4 x1 = *(const float4*)&h1s[256 + 4 * l];
            float4 y0 = *(const float4*)&h2s[4 * l];
            float4 y1 = *(const float4*)&h2s[256 + 4 * l];
            float a1 = dot4(w22a, x0) + dot4(w22b, x1);
            float a2 = dot4(dw22a, x0) + dot4(dw22b, x1);
            float b3 = dot4(u22a, y0) + dot4(u22b, y1);
            float b4 = dot4(du22a, y0) + dot4(du22b, y1);
            a1 = wave_reduce64(a1);
            a2 = wave_reduce64(a2);
            b3 = wave_reduce64(b3);
            b4 = wave_reduce64(b4);
            if (l == 0) {
                Mb[16 + wv] = a1; Mb[24 + wv] = a2;
                Mb[32 + wv] = b3; Mb[40 + wv] = b4;
            }
        }
        __syncthreads();

        // ---- phase 4: layer-2 gates + output ----
        {
            float m1 = Mb[16 + f8], m2 = Mb[24 + f8];
            float m3 = Mb[32 + f8], m4 = Mb[40 + f8];
            float g0 = cW2[0] * m1 + cdW2[0] * m2 + cU2[0] * m3 + cdU2[0] * m4 + bb2[0];
            float g1 = cW2[1] * m1 + cdW2[1] * m2 + cU2[1] * m3 + cdU2[1] * m4 + bb2[1];
            float g2 = cW2[2] * m1 + cdW2[2] * m2 + cU2[2] * m3 + cdU2[2] * m4 + bb2[2];
            float g3 = cW2[3] * m1 + cdW2[3] * m2 + cU2[3] * m3 + cdU2[3] * m4 + bb2[3];
            float ig = sigm(g0), fg = sigm(g1), gg = tanh_fast(g2), og = sigm(g3);
            c2 = fg * c2 + ig * gg;
            h2v = og * tanh_fast(c2);
            h2s[tid] = h2v;
            outb[(size_t)t * NH + tid] = h2v;
        }
        __syncthreads();
    }

    // --- final states: hn (2,B,H) then cn (2,B,H) after hidden_seq ---
    float* hn = out + (size_t)NB * NS * NH;
    float* cn = hn + (size_t)2 * NB * NH;
    hn[(size_t)b * NH + tid] = h1v;
    hn[(size_t)NB * NH + (size_t)b * NH + tid] = h2v;
    cn[(size_t)b * NH + tid] = c1;
    cn[(size_t)NB * NH + (size_t)b * NH + tid] = c2;
}

extern "C" void kernel_launch(void* const* d_in, const int* in_sizes, int n_in,
                              void* d_out, int out_size, void* d_ws, size_t ws_size,
                              hipStream_t stream) {
    const float* x = (const float*)d_in[0];
    const float* h0 = (const float*)d_in[1];
    const float* c0 = (const float*)d_in[2];
    const float* W11 = (const float*)d_in[3];
    const float* W12 = (const float*)d_in[4];
    const float* U11 = (const float*)d_in[5];
    const float* U12 = (const float*)d_in[6];
    const float* dW11 = (const float*)d_in[7];
    const float* dW12 = (const float*)d_in[8];
    const float* dU11 = (const float*)d_in[9];
    const float* dU12 = (const float*)d_in[10];
    const float* b11 = (const float*)d_in[11];
    const float* b12 = (const float*)d_in[12];
    const float* W21 = (const float*)d_in[13];
    const float* W22 = (const float*)d_in[14];
    const float* U21 = (const float*)d_in[15];
    const float* U22 = (const float*)d_in[16];
    const float* dW21 = (const float*)d_in[17];
    const float* dW22 = (const float*)d_in[18];
    const float* dU21 = (const float*)d_in[19];
    const float* dU22 = (const float*)d_in[20];
    const float* b21 = (const float*)d_in[21];
    const float* b22 = (const float*)d_in[22];

    float* P = (float*)d_ws;  // (B*S, 16) = 2 MB
    float* out = (float*)d_out;

    hipLaunchKernelGGL(precomp_kernel, dim3(NB * NS), dim3(64), 0, stream,
                       x, W12, dW12, P);
    hipLaunchKernelGGL(lstm_kernel, dim3(NB), dim3(512), 0, stream,
                       P, h0, c0,
                       W11, U11, dW11, dU11, U12, dU12, b11, b12,
                       W21, U21, dW21, dU21, W22, dW22, U22, dU22, b21, b22,
                       out);
}

// Round 2
// 1019.376 us; speedup vs baseline: 1.0787x; 1.0787x over previous
//
#include <hip/hip_runtime.h>
#include <math.h>

#define NB 64       // batch
#define NS 512      // seq len
#define ND 512      // input dim
#define NH 512      // hidden
// F = 8 factor rows, G = 256

__device__ __forceinline__ float dot4(float4 a, float4 b) {
    return a.x * b.x + a.y * b.y + a.z * b.z + a.w * b.w;
}

__device__ __forceinline__ float sigm(float x) {
    return 1.0f / (1.0f + __expf(-x));
}

__device__ __forceinline__ float tanh_fast(float x) {
    // safe for large |x|: e -> inf gives r -> 1
    float ax = fabsf(x);
    float e = __expf(2.0f * ax);
    float r = 1.0f - 2.0f / (e + 1.0f);
    return copysignf(r, x);
}

// ---------------------------------------------------------------------------
// Kernel A: P[bt][0..7] = W12 @ x_bt, P[bt][8..15] = dW12 @ x_bt
// one wave per (b,t) row
// ---------------------------------------------------------------------------
__global__ __launch_bounds__(64) void precomp_kernel(
    const float* __restrict__ x, const float* __restrict__ W12,
    const float* __restrict__ dW12, float* __restrict__ P) {
    int bt = blockIdx.x;
    int l = threadIdx.x;  // 0..63
    const float4* xr = (const float4*)(x + (size_t)bt * ND);
    float4 xv0 = xr[l];        // k = 4l..4l+3
    float4 xv1 = xr[64 + l];   // k = 256+4l..

    float acc[16];
#pragma unroll
    for (int f = 0; f < 8; ++f) {
        const float4* w = (const float4*)(W12 + f * ND);
        acc[f] = dot4(w[l], xv0) + dot4(w[64 + l], xv1);
        const float4* dw = (const float4*)(dW12 + f * ND);
        acc[8 + f] = dot4(dw[l], xv0) + dot4(dw[64 + l], xv1);
    }
#pragma unroll
    for (int off = 1; off < 64; off <<= 1) {
#pragma unroll
        for (int f = 0; f < 16; ++f) acc[f] += __shfl_xor(acc[f], off, 64);
    }

    if (l == 0) {
        float4* o = (float4*)(P + (size_t)bt * 16);
        o[0] = make_float4(acc[0], acc[1], acc[2], acc[3]);
        o[1] = make_float4(acc[4], acc[5], acc[6], acc[7]);
        o[2] = make_float4(acc[8], acc[9], acc[10], acc[11]);
        o[3] = make_float4(acc[12], acc[13], acc[14], acc[15]);
    }
}

// ---------------------------------------------------------------------------
// Kernel B: persistent recurrence — one workgroup per batch element.
// 512 threads = 8 waves. Wave w owns factor row f=w for all 6 dot products.
// 2 phases / 2 barriers per timestep:
//   Phase A: 6 reductions (W22,dW22,U12,dU12 on h1(t+1); U22,dU22 on h2(t))
//   Phase B: L2 gates at t (-> h2(t+1), out[t]) and L1 gates at t+1
//            (-> h1(t+2)) — independent VALU work, fused.
// ---------------------------------------------------------------------------
__global__ __launch_bounds__(512) void lstm_kernel(
    const float* __restrict__ P, const float* __restrict__ h0,
    const float* __restrict__ c0,
    const float* __restrict__ W11, const float* __restrict__ U11,
    const float* __restrict__ dW11, const float* __restrict__ dU11,
    const float* __restrict__ U12, const float* __restrict__ dU12,
    const float* __restrict__ b11, const float* __restrict__ b12,
    const float* __restrict__ W21, const float* __restrict__ U21,
    const float* __restrict__ dW21, const float* __restrict__ dU21,
    const float* __restrict__ W22, const float* __restrict__ dW22,
    const float* __restrict__ U22, const float* __restrict__ dU22,
    const float* __restrict__ b21, const float* __restrict__ b22,
    float* __restrict__ out) {
    int b = blockIdx.x;
    int tid = threadIdx.x;       // 0..511 == hidden index h
    int wv = tid >> 6;           // wave -> factor row f
    int l = tid & 63;            // lane

    __shared__ float h1s[NH];
    __shared__ float h2s[NH];
    __shared__ float Mb[48];  // [0..7]=W22·h1 [8..15]=dW22·h1 [16..23]=U12·h1
                              // [24..31]=dU12·h1 [32..39]=U22·h2 [40..47]=dU22·h2

    // --- per-wave dot-product weights into registers (fixed for all steps) ---
    const float4* pU12 = (const float4*)(U12 + wv * NH);
    const float4* pdU12 = (const float4*)(dU12 + wv * NH);
    const float4* pW22 = (const float4*)(W22 + wv * NH);
    const float4* pdW22 = (const float4*)(dW22 + wv * NH);
    const float4* pU22 = (const float4*)(U22 + wv * NH);
    const float4* pdU22 = (const float4*)(dU22 + wv * NH);
    float4 u12a = pU12[l], u12b = pU12[64 + l];
    float4 du12a = pdU12[l], du12b = pdU12[64 + l];
    float4 w22a = pW22[l], w22b = pW22[64 + l];
    float4 dw22a = pdW22[l], dw22b = pdW22[64 + l];
    float4 u22a = pU22[l], u22b = pU22[64 + l];
    float4 du22a = pdU22[l], du22b = pdU22[64 + l];

    // --- per-thread gate coefficients (fixed for all steps) ---
    float cW1[4], cdW1[4], cU1[4], cdU1[4], bb1[4];
    float cW2[4], cdW2[4], cU2[4], cdU2[4], bb2[4];
#pragma unroll
    for (int q = 0; q < 4; ++q) {
        int idx = q * 64 + (tid >> 3);
        cW1[q] = W11[idx]; cdW1[q] = dW11[idx];
        cU1[q] = U11[idx]; cdU1[q] = dU11[idx];
        bb1[q] = b11[q * NH + tid] + b12[q * NH + tid];
        cW2[q] = W21[idx]; cdW2[q] = dW21[idx];
        cU2[q] = U21[idx]; cdU2[q] = dU21[idx];
        bb2[q] = b21[q * NH + tid] + b22[q * NH + tid];
    }

    // --- initial state ---
    float c1 = c0[(size_t)b * NH + tid];
    float c2 = c0[(size_t)NB * NH + (size_t)b * NH + tid];
    h1s[tid] = h0[(size_t)b * NH + tid];
    h2s[tid] = h0[(size_t)NB * NH + (size_t)b * NH + tid];
    float h1v = h1s[tid], h2v = h2s[tid];
    __syncthreads();

    const float* Pb = P + (size_t)b * NS * 16;
    float* outb = out + (size_t)b * NS * NH;
    int f8 = tid & 7;

    // ---- prologue: compute h1(1) from h1(0), x(0) ----
    {
        float p1 = Pb[f8];
        float p2 = Pb[8 + f8];
        float4 x0 = *(const float4*)&h1s[4 * l];
        float4 x1 = *(const float4*)&h1s[256 + 4 * l];
        float r3 = dot4(u12a, x0) + dot4(u12b, x1);
        float r4 = dot4(du12a, x0) + dot4(du12b, x1);
#pragma unroll
        for (int off = 1; off < 64; off <<= 1) {
            r3 += __shfl_xor(r3, off, 64);
            r4 += __shfl_xor(r4, off, 64);
        }
        if (l == 0) { Mb[16 + wv] = r3; Mb[24 + wv] = r4; }
        __syncthreads();
        float m3 = Mb[16 + f8], m4 = Mb[24 + f8];
        float g0 = cW1[0] * p1 + cdW1[0] * p2 + cU1[0] * m3 + cdU1[0] * m4 + bb1[0];
        float g1 = cW1[1] * p1 + cdW1[1] * p2 + cU1[1] * m3 + cdU1[1] * m4 + bb1[1];
        float g2 = cW1[2] * p1 + cdW1[2] * p2 + cU1[2] * m3 + cdU1[2] * m4 + bb1[2];
        float g3 = cW1[3] * p1 + cdW1[3] * p2 + cU1[3] * m3 + cdU1[3] * m4 + bb1[3];
        float ig = sigm(g0), fg = sigm(g1), gg = tanh_fast(g2), og = sigm(g3);
        c1 = fg * c1 + ig * gg;
        h1v = og * tanh_fast(c1);
        h1s[tid] = h1v;
        __syncthreads();
    }

    // ---- steady state: h1s = h1(t+1), h2s = h2(t) at top of iteration t ----
    for (int t = 0; t < NS; ++t) {
        // prefetch L1 input contribution for step t+1 (clamped; unused at t=NS-1)
        int tp = (t + 1 < NS) ? t + 1 : t;
        float p1 = Pb[tp * 16 + f8];
        float p2 = Pb[tp * 16 + 8 + f8];

        // ---- phase A: 6 fused reductions ----
        float4 x0 = *(const float4*)&h1s[4 * l];
        float4 x1 = *(const float4*)&h1s[256 + 4 * l];
        float4 y0 = *(const float4*)&h2s[4 * l];
        float4 y1 = *(const float4*)&h2s[256 + 4 * l];
        float r1 = dot4(w22a, x0) + dot4(w22b, x1);
        float r2 = dot4(dw22a, x0) + dot4(dw22b, x1);
        float r3 = dot4(u12a, x0) + dot4(u12b, x1);
        float r4 = dot4(du12a, x0) + dot4(du12b, x1);
        float r5 = dot4(u22a, y0) + dot4(u22b, y1);
        float r6 = dot4(du22a, y0) + dot4(du22b, y1);
#pragma unroll
        for (int off = 1; off < 64; off <<= 1) {
            r1 += __shfl_xor(r1, off, 64);
            r2 += __shfl_xor(r2, off, 64);
            r3 += __shfl_xor(r3, off, 64);
            r4 += __shfl_xor(r4, off, 64);
            r5 += __shfl_xor(r5, off, 64);
            r6 += __shfl_xor(r6, off, 64);
        }
        if (l == 0) {
            Mb[wv] = r1; Mb[8 + wv] = r2;
            Mb[16 + wv] = r3; Mb[24 + wv] = r4;
            Mb[32 + wv] = r5; Mb[40 + wv] = r6;
        }
        __syncthreads();

        // ---- phase B: L2 gates at t AND L1 gates at t+1 (independent) ----
        {
            float m1 = Mb[f8], m2 = Mb[8 + f8];
            float m5 = Mb[32 + f8], m6 = Mb[40 + f8];
            float g0 = cW2[0] * m1 + cdW2[0] * m2 + cU2[0] * m5 + cdU2[0] * m6 + bb2[0];
            float g1 = cW2[1] * m1 + cdW2[1] * m2 + cU2[1] * m5 + cdU2[1] * m6 + bb2[1];
            float g2 = cW2[2] * m1 + cdW2[2] * m2 + cU2[2] * m5 + cdU2[2] * m6 + bb2[2];
            float g3 = cW2[3] * m1 + cdW2[3] * m2 + cU2[3] * m5 + cdU2[3] * m6 + bb2[3];
            float ig = sigm(g0), fg = sigm(g1), gg = tanh_fast(g2), og = sigm(g3);
            c2 = fg * c2 + ig * gg;
            h2v = og * tanh_fast(c2);
            h2s[tid] = h2v;
            outb[(size_t)t * NH + tid] = h2v;
        }
        if (t < NS - 1) {
            float m3 = Mb[16 + f8], m4 = Mb[24 + f8];
            float g0 = cW1[0] * p1 + cdW1[0] * p2 + cU1[0] * m3 + cdU1[0] * m4 + bb1[0];
            float g1 = cW1[1] * p1 + cdW1[1] * p2 + cU1[1] * m3 + cdU1[1] * m4 + bb1[1];
            float g2 = cW1[2] * p1 + cdW1[2] * p2 + cU1[2] * m3 + cdU1[2] * m4 + bb1[2];
            float g3 = cW1[3] * p1 + cdW1[3] * p2 + cU1[3] * m3 + cdU1[3] * m4 + bb1[3];
            float ig = sigm(g0), fg = sigm(g1), gg = tanh_fast(g2), og = sigm(g3);
            c1 = fg * c1 + ig * gg;
            h1v = og * tanh_fast(c1);
            h1s[tid] = h1v;
        }
        __syncthreads();
    }

    // --- final states: hn (2,B,H) then cn (2,B,H) after hidden_seq ---
    float* hn = out + (size_t)NB * NS * NH;
    float* cn = hn + (size_t)2 * NB * NH;
    hn[(size_t)b * NH + tid] = h1v;
    hn[(size_t)NB * NH + (size_t)b * NH + tid] = h2v;
    cn[(size_t)b * NH + tid] = c1;
    cn[(size_t)NB * NH + (size_t)b * NH + tid] = c2;
}

extern "C" void kernel_launch(void* const* d_in, const int* in_sizes, int n_in,
                              void* d_out, int out_size, void* d_ws, size_t ws_size,
                              hipStream_t stream) {
    const float* x = (const float*)d_in[0];
    const float* h0 = (const float*)d_in[1];
    const float* c0 = (const float*)d_in[2];
    const float* W11 = (const float*)d_in[3];
    const float* W12 = (const float*)d_in[4];
    const float* U11 = (const float*)d_in[5];
    const float* U12 = (const float*)d_in[6];
    const float* dW11 = (const float*)d_in[7];
    const float* dW12 = (const float*)d_in[8];
    const float* dU11 = (const float*)d_in[9];
    const float* dU12 = (const float*)d_in[10];
    const float* b11 = (const float*)d_in[11];
    const float* b12 = (const float*)d_in[12];
    const float* W21 = (const float*)d_in[13];
    const float* W22 = (const float*)d_in[14];
    const float* U21 = (const float*)d_in[15];
    const float* U22 = (const float*)d_in[16];
    const float* dW21 = (const float*)d_in[17];
    const float* dW22 = (const float*)d_in[18];
    const float* dU21 = (const float*)d_in[19];
    const float* dU22 = (const float*)d_in[20];
    const float* b21 = (const float*)d_in[21];
    const float* b22 = (const float*)d_in[22];

    float* P = (float*)d_ws;  // (B*S, 16) = 2 MB
    float* out = (float*)d_out;

    hipLaunchKernelGGL(precomp_kernel, dim3(NB * NS), dim3(64), 0, stream,
                       x, W12, dW12, P);
    hipLaunchKernelGGL(lstm_kernel, dim3(NB), dim3(512), 0, stream,
                       P, h0, c0,
                       W11, U11, dW11, dU11, U12, dU12, b11, b12,
                       W21, U21, dW21, dU21, W22, dW22, U22, dU22, b21, b22,
                       out);
}

// Round 3
// 707.488 us; speedup vs baseline: 1.5542x; 1.4408x over previous
//
#include <hip/hip_runtime.h>
#include <math.h>

#define NB 64       // batch
#define NS 512      // seq len
#define ND 512      // input dim
#define NH 512      // hidden
// F = 8 factor rows, G = 256

__device__ __forceinline__ float dot4(float4 a, float4 b) {
    return a.x * b.x + a.y * b.y + a.z * b.z + a.w * b.w;
}

// 64-lane sum via DPP (VALU only, no LDS). Total ends in lane 63.
__device__ __forceinline__ float dpp_sum64(float x) {
    x += __int_as_float(__builtin_amdgcn_update_dpp(0, __float_as_int(x), 0x111, 0xf, 0xf, true)); // row_shr:1
    x += __int_as_float(__builtin_amdgcn_update_dpp(0, __float_as_int(x), 0x112, 0xf, 0xf, true)); // row_shr:2
    x += __int_as_float(__builtin_amdgcn_update_dpp(0, __float_as_int(x), 0x114, 0xf, 0xf, true)); // row_shr:4
    x += __int_as_float(__builtin_amdgcn_update_dpp(0, __float_as_int(x), 0x118, 0xf, 0xf, true)); // row_shr:8
    x += __int_as_float(__builtin_amdgcn_update_dpp(0, __float_as_int(x), 0x142, 0xa, 0xf, true)); // row_bcast:15
    x += __int_as_float(__builtin_amdgcn_update_dpp(0, __float_as_int(x), 0x143, 0xc, 0xf, true)); // row_bcast:31
    return x;
}

// broadcast lane 63 to all lanes (lands in an SGPR)
__device__ __forceinline__ float bcast63(float x) {
    return __int_as_float(__builtin_amdgcn_readlane(__float_as_int(x), 63));
}

__device__ __forceinline__ float sigm(float x) {
    return 1.0f / (1.0f + __expf(-x));
}

__device__ __forceinline__ float tanh_fast(float x) {
    float ax = fabsf(x);
    float e = __expf(2.0f * ax);
    float r = 1.0f - 2.0f / (e + 1.0f);
    return copysignf(r, x);
}

// ---------------------------------------------------------------------------
// Kernel A: P[bt][0..7] = W12 @ x_bt, P[bt][8..15] = dW12 @ x_bt
// ---------------------------------------------------------------------------
__global__ __launch_bounds__(64) void precomp_kernel(
    const float* __restrict__ x, const float* __restrict__ W12,
    const float* __restrict__ dW12, float* __restrict__ P) {
    int bt = blockIdx.x;
    int l = threadIdx.x;  // 0..63
    const float4* xr = (const float4*)(x + (size_t)bt * ND);
    float4 xv0 = xr[l];
    float4 xv1 = xr[64 + l];

    float acc[16];
#pragma unroll
    for (int f = 0; f < 8; ++f) {
        const float4* w = (const float4*)(W12 + f * ND);
        acc[f] = dot4(w[l], xv0) + dot4(w[64 + l], xv1);
        const float4* dw = (const float4*)(dW12 + f * ND);
        acc[8 + f] = dot4(dw[l], xv0) + dot4(dw[64 + l], xv1);
    }
#pragma unroll
    for (int f = 0; f < 16; ++f) acc[f] = dpp_sum64(acc[f]);

    if (l == 63) {
        float4* o = (float4*)(P + (size_t)bt * 16);
        o[0] = make_float4(acc[0], acc[1], acc[2], acc[3]);
        o[1] = make_float4(acc[4], acc[5], acc[6], acc[7]);
        o[2] = make_float4(acc[8], acc[9], acc[10], acc[11]);
        o[3] = make_float4(acc[12], acc[13], acc[14], acc[15]);
    }
}

// ---------------------------------------------------------------------------
// Kernel B: persistent recurrence — one workgroup per batch element.
// 8 waves; wave w owns factor row w of all 6 reductions AND gate rows
// h = 8*lane + w (h&7 == w), so reduction results broadcast in-wave via
// readlane — no LDS exchange for the m-values. h1s/h2s double-buffered:
// ONE barrier per timestep.
// ---------------------------------------------------------------------------
__global__ __launch_bounds__(512) void lstm_kernel(
    const float* __restrict__ P, const float* __restrict__ h0,
    const float* __restrict__ c0,
    const float* __restrict__ W11, const float* __restrict__ U11,
    const float* __restrict__ dW11, const float* __restrict__ dU11,
    const float* __restrict__ U12, const float* __restrict__ dU12,
    const float* __restrict__ b11, const float* __restrict__ b12,
    const float* __restrict__ W21, const float* __restrict__ U21,
    const float* __restrict__ dW21, const float* __restrict__ dU21,
    const float* __restrict__ W22, const float* __restrict__ dW22,
    const float* __restrict__ U22, const float* __restrict__ dU22,
    const float* __restrict__ b21, const float* __restrict__ b22,
    float* __restrict__ out) {
    int b = blockIdx.x;
    int tid = threadIdx.x;
    int wv = tid >> 6;           // wave = factor row
    int l = tid & 63;            // lane
    int h = 8 * l + wv;          // owned hidden row (h & 7 == wv, h >> 3 == l)

    __shared__ float h1s[2][NH];
    __shared__ float h2s[2][NH];

    // --- per-wave dot-product weights (factor row wv) ---
    const float4* pU12 = (const float4*)(U12 + wv * NH);
    const float4* pdU12 = (const float4*)(dU12 + wv * NH);
    const float4* pW22 = (const float4*)(W22 + wv * NH);
    const float4* pdW22 = (const float4*)(dW22 + wv * NH);
    const float4* pU22 = (const float4*)(U22 + wv * NH);
    const float4* pdU22 = (const float4*)(dU22 + wv * NH);
    float4 u12a = pU12[l], u12b = pU12[64 + l];
    float4 du12a = pdU12[l], du12b = pdU12[64 + l];
    float4 w22a = pW22[l], w22b = pW22[64 + l];
    float4 dw22a = pdW22[l], dw22b = pdW22[64 + l];
    float4 u22a = pU22[l], u22b = pU22[64 + l];
    float4 du22a = pdU22[l], du22b = pdU22[64 + l];

    // --- per-thread gate coefficients for owned row h ---
    float cW1[4], cdW1[4], cU1[4], cdU1[4], bb1[4];
    float cW2[4], cdW2[4], cU2[4], cdU2[4], bb2[4];
#pragma unroll
    for (int q = 0; q < 4; ++q) {
        int idx = q * 64 + l;  // (q*512 + h) / 8
        cW1[q] = W11[idx]; cdW1[q] = dW11[idx];
        cU1[q] = U11[idx]; cdU1[q] = dU11[idx];
        bb1[q] = b11[q * NH + h] + b12[q * NH + h];
        cW2[q] = W21[idx]; cdW2[q] = dW21[idx];
        cU2[q] = U21[idx]; cdU2[q] = dU21[idx];
        bb2[q] = b21[q * NH + h] + b22[q * NH + h];
    }

    // --- initial state ---
    float c1 = c0[(size_t)b * NH + h];
    float c2 = c0[(size_t)NB * NH + (size_t)b * NH + h];
    float h1v = h0[(size_t)b * NH + h];
    float h2v = h0[(size_t)NB * NH + (size_t)b * NH + h];
    h1s[0][tid] = h0[(size_t)b * NH + tid];
    h2s[0][tid] = h0[(size_t)NB * NH + (size_t)b * NH + tid];
    __syncthreads();

    const float* Pb = P + (size_t)b * NS * 16;
    float* outb = out + (size_t)b * NS * NH;

    // ---- prologue: h1(1) from h1(0), x(0) -> h1s[0] ----
    {
        float p1 = Pb[wv];
        float p2 = Pb[8 + wv];
        float4 x0 = *(const float4*)&h1s[0][4 * l];
        float4 x1 = *(const float4*)&h1s[0][256 + 4 * l];
        float r3 = dot4(u12a, x0) + dot4(u12b, x1);
        float r4 = dot4(du12a, x0) + dot4(du12b, x1);
        float m3 = bcast63(dpp_sum64(r3));
        float m4 = bcast63(dpp_sum64(r4));
        __syncthreads();  // WAR: all reads of h1s[0] done before overwrite
        float g0 = cW1[0] * p1 + cdW1[0] * p2 + cU1[0] * m3 + cdU1[0] * m4 + bb1[0];
        float g1 = cW1[1] * p1 + cdW1[1] * p2 + cU1[1] * m3 + cdU1[1] * m4 + bb1[1];
        float g2 = cW1[2] * p1 + cdW1[2] * p2 + cU1[2] * m3 + cdU1[2] * m4 + bb1[2];
        float g3 = cW1[3] * p1 + cdW1[3] * p2 + cU1[3] * m3 + cdU1[3] * m4 + bb1[3];
        float ig = sigm(g0), fg = sigm(g1), gg = tanh_fast(g2), og = sigm(g3);
        c1 = fg * c1 + ig * gg;
        h1v = og * tanh_fast(c1);
        h1s[0][h] = h1v;
        __syncthreads();  // RAW
    }

    // ---- steady state: at top of iter t, buf p=t&1 holds h1(t+1), h2(t) ----
    for (int t = 0; t < NS; ++t) {
        const int p = t & 1;
        int tp = (t + 1 < NS) ? t + 1 : t;
        float p1 = Pb[tp * 16 + wv];
        float p2 = Pb[tp * 16 + 8 + wv];

        float4 x0 = *(const float4*)&h1s[p][4 * l];
        float4 x1 = *(const float4*)&h1s[p][256 + 4 * l];
        float4 y0 = *(const float4*)&h2s[p][4 * l];
        float4 y1 = *(const float4*)&h2s[p][256 + 4 * l];

        // deferred coalesced store of out[t-1] = h2(t) (registers y0/y1)
        if (t > 0 && wv == 0)
            *(float4*)&outb[(size_t)(t - 1) * NH + 4 * l] = y0;
        if (t > 0 && wv == 1)
            *(float4*)&outb[(size_t)(t - 1) * NH + 256 + 4 * l] = y1;

        float r1 = dot4(w22a, x0) + dot4(w22b, x1);
        float r2 = dot4(dw22a, x0) + dot4(dw22b, x1);
        float r3 = dot4(u12a, x0) + dot4(u12b, x1);
        float r4 = dot4(du12a, x0) + dot4(du12b, x1);
        float r5 = dot4(u22a, y0) + dot4(u22b, y1);
        float r6 = dot4(du22a, y0) + dot4(du22b, y1);
        r1 = dpp_sum64(r1);
        r2 = dpp_sum64(r2);
        r3 = dpp_sum64(r3);
        r4 = dpp_sum64(r4);
        r5 = dpp_sum64(r5);
        r6 = dpp_sum64(r6);
        float m1 = bcast63(r1), m2 = bcast63(r2), m3 = bcast63(r3);
        float m4 = bcast63(r4), m5 = bcast63(r5), m6 = bcast63(r6);

        // ---- L2 gates at t -> h2(t+1) ----
        {
            float g0 = cW2[0] * m1 + cdW2[0] * m2 + cU2[0] * m5 + cdU2[0] * m6 + bb2[0];
            float g1 = cW2[1] * m1 + cdW2[1] * m2 + cU2[1] * m5 + cdU2[1] * m6 + bb2[1];
            float g2 = cW2[2] * m1 + cdW2[2] * m2 + cU2[2] * m5 + cdU2[2] * m6 + bb2[2];
            float g3 = cW2[3] * m1 + cdW2[3] * m2 + cU2[3] * m5 + cdU2[3] * m6 + bb2[3];
            float ig = sigm(g0), fg = sigm(g1), gg = tanh_fast(g2), og = sigm(g3);
            c2 = fg * c2 + ig * gg;
            h2v = og * tanh_fast(c2);
            h2s[p ^ 1][h] = h2v;
        }
        // ---- L1 gates at t+1 -> h1(t+2) ----
        if (t < NS - 1) {
            float g0 = cW1[0] * p1 + cdW1[0] * p2 + cU1[0] * m3 + cdU1[0] * m4 + bb1[0];
            float g1 = cW1[1] * p1 + cdW1[1] * p2 + cU1[1] * m3 + cdU1[1] * m4 + bb1[1];
            float g2 = cW1[2] * p1 + cdW1[2] * p2 + cU1[2] * m3 + cdU1[2] * m4 + bb1[2];
            float g3 = cW1[3] * p1 + cdW1[3] * p2 + cU1[3] * m3 + cdU1[3] * m4 + bb1[3];
            float ig = sigm(g0), fg = sigm(g1), gg = tanh_fast(g2), og = sigm(g3);
            c1 = fg * c1 + ig * gg;
            h1v = og * tanh_fast(c1);
            h1s[p ^ 1][h] = h1v;
        }
        __syncthreads();  // single barrier: RAW for buf p^1 (WAR-free by dbuf)
    }

    // out[NS-1] = h2(NS): last write went to buffer ((NS-1)&1)^1 == 0
    outb[(size_t)(NS - 1) * NH + tid] = h2s[0][tid];

    // --- final states: hn (2,B,H) then cn (2,B,H) ---
    float* hn = out + (size_t)NB * NS * NH;
    float* cn = hn + (size_t)2 * NB * NH;
    hn[(size_t)b * NH + h] = h1v;
    hn[(size_t)NB * NH + (size_t)b * NH + h] = h2v;
    cn[(size_t)b * NH + h] = c1;
    cn[(size_t)NB * NH + (size_t)b * NH + h] = c2;
}

extern "C" void kernel_launch(void* const* d_in, const int* in_sizes, int n_in,
                              void* d_out, int out_size, void* d_ws, size_t ws_size,
                              hipStream_t stream) {
    const float* x = (const float*)d_in[0];
    const float* h0 = (const float*)d_in[1];
    const float* c0 = (const float*)d_in[2];
    const float* W11 = (const float*)d_in[3];
    const float* W12 = (const float*)d_in[4];
    const float* U11 = (const float*)d_in[5];
    const float* U12 = (const float*)d_in[6];
    const float* dW11 = (const float*)d_in[7];
    const float* dW12 = (const float*)d_in[8];
    const float* dU11 = (const float*)d_in[9];
    const float* dU12 = (const float*)d_in[10];
    const float* b11 = (const float*)d_in[11];
    const float* b12 = (const float*)d_in[12];
    const float* W21 = (const float*)d_in[13];
    const float* W22 = (const float*)d_in[14];
    const float* U21 = (const float*)d_in[15];
    const float* U22 = (const float*)d_in[16];
    const float* dW21 = (const float*)d_in[17];
    const float* dW22 = (const float*)d_in[18];
    const float* dU21 = (const float*)d_in[19];
    const float* dU22 = (const float*)d_in[20];
    const float* b21 = (const float*)d_in[21];
    const float* b22 = (const float*)d_in[22];

    float* P = (float*)d_ws;  // (B*S, 16) = 2 MB
    float* out = (float*)d_out;

    hipLaunchKernelGGL(precomp_kernel, dim3(NB * NS), dim3(64), 0, stream,
                       x, W12, dW12, P);
    hipLaunchKernelGGL(lstm_kernel, dim3(NB), dim3(512), 0, stream,
                       P, h0, c0,
                       W11, U11, dW11, dU11, U12, dU12, b11, b12,
                       W21, U21, dW21, dU21, W22, dW22, U22, dU22, b21, b22,
                       out);
}

// Round 4
// 703.944 us; speedup vs baseline: 1.5620x; 1.0050x over previous
//
#include <hip/hip_runtime.h>
#include <math.h>

#define NB 64       // batch
#define NS 512      // seq len
#define ND 512      // input dim
#define NH 512      // hidden
// F = 8 factor rows, G = 256

__device__ __forceinline__ float dot4(float4 a, float4 b) {
    return a.x * b.x + a.y * b.y + a.z * b.z + a.w * b.w;
}

// 64-lane sum via DPP (VALU only, no LDS). Total ends in lane 63.
__device__ __forceinline__ float dpp_sum64(float x) {
    x += __int_as_float(__builtin_amdgcn_update_dpp(0, __float_as_int(x), 0x111, 0xf, 0xf, true)); // row_shr:1
    x += __int_as_float(__builtin_amdgcn_update_dpp(0, __float_as_int(x), 0x112, 0xf, 0xf, true)); // row_shr:2
    x += __int_as_float(__builtin_amdgcn_update_dpp(0, __float_as_int(x), 0x114, 0xf, 0xf, true)); // row_shr:4
    x += __int_as_float(__builtin_amdgcn_update_dpp(0, __float_as_int(x), 0x118, 0xf, 0xf, true)); // row_shr:8
    x += __int_as_float(__builtin_amdgcn_update_dpp(0, __float_as_int(x), 0x142, 0xa, 0xf, true)); // row_bcast:15
    x += __int_as_float(__builtin_amdgcn_update_dpp(0, __float_as_int(x), 0x143, 0xc, 0xf, true)); // row_bcast:31
    return x;
}

__device__ __forceinline__ float bcast63(float x) {
    return __int_as_float(__builtin_amdgcn_readlane(__float_as_int(x), 63));
}

__device__ __forceinline__ float sigm(float x) {
    return 1.0f / (1.0f + __expf(-x));
}

__device__ __forceinline__ float tanh_fast(float x) {
    float ax = fabsf(x);
    float e = __expf(2.0f * ax);
    float r = 1.0f - 2.0f / (e + 1.0f);
    return copysignf(r, x);
}

// Workgroup barrier WITHOUT vmcnt drain: own LDS ops complete, then barrier.
// Global stores/loads stay in flight across steps.
__device__ __forceinline__ void wg_barrier() {
    asm volatile("s_waitcnt lgkmcnt(0)\n\ts_barrier" ::: "memory");
}

// ---------------------------------------------------------------------------
// Kernel A: P[bt][2f] = (W12 @ x_bt)[f], P[bt][2f+1] = (dW12 @ x_bt)[f]
// (interleaved so the recurrence loads one float2 per factor row)
// ---------------------------------------------------------------------------
__global__ __launch_bounds__(64) void precomp_kernel(
    const float* __restrict__ x, const float* __restrict__ W12,
    const float* __restrict__ dW12, float* __restrict__ P) {
    int bt = blockIdx.x;
    int l = threadIdx.x;  // 0..63
    const float4* xr = (const float4*)(x + (size_t)bt * ND);
    float4 xv0 = xr[l];
    float4 xv1 = xr[64 + l];

    float acc[16];
#pragma unroll
    for (int f = 0; f < 8; ++f) {
        const float4* w = (const float4*)(W12 + f * ND);
        acc[f] = dot4(w[l], xv0) + dot4(w[64 + l], xv1);
        const float4* dw = (const float4*)(dW12 + f * ND);
        acc[8 + f] = dot4(dw[l], xv0) + dot4(dw[64 + l], xv1);
    }
#pragma unroll
    for (int f = 0; f < 16; ++f) acc[f] = dpp_sum64(acc[f]);

    if (l == 63) {
        float4* o = (float4*)(P + (size_t)bt * 16);
        o[0] = make_float4(acc[0], acc[8], acc[1], acc[9]);
        o[1] = make_float4(acc[2], acc[10], acc[3], acc[11]);
        o[2] = make_float4(acc[4], acc[12], acc[5], acc[13]);
        o[3] = make_float4(acc[6], acc[14], acc[7], acc[15]);
    }
}

// ---------------------------------------------------------------------------
// Kernel B: persistent recurrence — one workgroup per batch element.
// 8 waves; wave w owns factor row w and gate rows h = 8*lane + w.
// LDS h-state is stored PERMUTED: slot s holds h(8*(s&63) + (s>>6)), so each
// thread's state write is hs[tid] (stride-1, conflict-free). Reads are
// contiguous float4 in permuted space; the 6 dot-weight vectors are gathered
// with the same permutation at startup (dots are order-invariant).
// Raw barrier (no vmcnt drain): ONE barrier per step, output stores in flight.
// ---------------------------------------------------------------------------
__global__ __launch_bounds__(512) void lstm_kernel(
    const float* __restrict__ P, const float* __restrict__ h0,
    const float* __restrict__ c0,
    const float* __restrict__ W11, const float* __restrict__ U11,
    const float* __restrict__ dW11, const float* __restrict__ dU11,
    const float* __restrict__ U12, const float* __restrict__ dU12,
    const float* __restrict__ b11, const float* __restrict__ b12,
    const float* __restrict__ W21, const float* __restrict__ U21,
    const float* __restrict__ dW21, const float* __restrict__ dU21,
    const float* __restrict__ W22, const float* __restrict__ dW22,
    const float* __restrict__ U22, const float* __restrict__ dU22,
    const float* __restrict__ b21, const float* __restrict__ b22,
    float* __restrict__ out) {
    int b = blockIdx.x;
    int tid = threadIdx.x;
    int wv = tid >> 6;           // wave = factor row
    int l = tid & 63;            // lane
    int h = 8 * l + wv;          // owned hidden row

    __shared__ float h1s[2][NH];
    __shared__ float h2s[2][NH];

    // --- permuted gather of the 6 dot-weight vectors (factor row wv) ---
    // x0.e corresponds to natural index kb + 8e; x1.e to kb + 4 + 8e.
    int kb = 32 * (l & 15) + (l >> 4);
    float4 u12a, u12b, du12a, du12b, w22a, w22b, dw22a, dw22b, u22a, u22b, du22a, du22b;
    {
        const float* M;
#define LOADW(mat, ra, rb)                                              \
        M = (mat) + wv * NH;                                            \
        ra = make_float4(M[kb], M[kb + 8], M[kb + 16], M[kb + 24]);     \
        rb = make_float4(M[kb + 4], M[kb + 12], M[kb + 20], M[kb + 28]);
        LOADW(U12, u12a, u12b)
        LOADW(dU12, du12a, du12b)
        LOADW(W22, w22a, w22b)
        LOADW(dW22, dw22a, dw22b)
        LOADW(U22, u22a, u22b)
        LOADW(dU22, du22a, du22b)
#undef LOADW
    }

    // --- per-thread gate coefficients for owned row h ---
    float cW1[4], cdW1[4], cU1[4], cdU1[4], bb1[4];
    float cW2[4], cdW2[4], cU2[4], cdU2[4], bb2[4];
#pragma unroll
    for (int q = 0; q < 4; ++q) {
        int idx = q * 64 + l;  // (q*512 + h) / 8
        cW1[q] = W11[idx]; cdW1[q] = dW11[idx];
        cU1[q] = U11[idx]; cdU1[q] = dU11[idx];
        bb1[q] = b11[q * NH + h] + b12[q * NH + h];
        cW2[q] = W21[idx]; cdW2[q] = dW21[idx];
        cU2[q] = U21[idx]; cdU2[q] = dU21[idx];
        bb2[q] = b21[q * NH + h] + b22[q * NH + h];
    }

    // --- initial state (slot tid holds exactly h = own row) ---
    float c1 = c0[(size_t)b * NH + h];
    float c2 = c0[(size_t)NB * NH + (size_t)b * NH + h];
    float h1v = h0[(size_t)b * NH + h];
    float h2v = h0[(size_t)NB * NH + (size_t)b * NH + h];
    h1s[0][tid] = h1v;
    h2s[0][tid] = h2v;
    wg_barrier();

    const float* Pb = P + (size_t)b * NS * 16;
    float* outb = out + (size_t)b * NS * NH;

    // ---- prologue: h1(1) from h1(0), x(0) -> h1s[0] ----
    {
        float2 pp = ((const float2*)Pb)[wv];
        float4 x0 = *(const float4*)&h1s[0][4 * l];
        float4 x1 = *(const float4*)&h1s[0][256 + 4 * l];
        float r3 = dot4(u12a, x0) + dot4(u12b, x1);
        float r4 = dot4(du12a, x0) + dot4(du12b, x1);
        float m3 = bcast63(dpp_sum64(r3));
        float m4 = bcast63(dpp_sum64(r4));
        wg_barrier();  // WAR: all reads of h1s[0] done before overwrite
        float g0 = cW1[0] * pp.x + cdW1[0] * pp.y + cU1[0] * m3 + cdU1[0] * m4 + bb1[0];
        float g1 = cW1[1] * pp.x + cdW1[1] * pp.y + cU1[1] * m3 + cdU1[1] * m4 + bb1[1];
        float g2 = cW1[2] * pp.x + cdW1[2] * pp.y + cU1[2] * m3 + cdU1[2] * m4 + bb1[2];
        float g3 = cW1[3] * pp.x + cdW1[3] * pp.y + cU1[3] * m3 + cdU1[3] * m4 + bb1[3];
        float ig = sigm(g0), fg = sigm(g1), gg = tanh_fast(g2), og = sigm(g3);
        c1 = fg * c1 + ig * gg;
        h1v = og * tanh_fast(c1);
        h1s[0][tid] = h1v;
        wg_barrier();  // RAW
    }

    // P prefetch for iter 0's L1 gates (step t+1 = 1)
    float p1, p2;
    {
        float2 pp = ((const float2*)(Pb + 16))[wv];
        p1 = pp.x; p2 = pp.y;
    }

    // ---- steady state: at top of iter t, buf p=t&1 holds h1(t+1), h2(t) ----
    for (int t = 0; t < NS; ++t) {
        const int p = t & 1;
        // prefetch P for next iteration's L1 gates (step t+2)
        int tn = (t + 2 < NS) ? t + 2 : NS - 1;
        float2 ppn = ((const float2*)(Pb + (size_t)tn * 16))[wv];

        float4 x0 = *(const float4*)&h1s[p][4 * l];
        float4 x1 = *(const float4*)&h1s[p][256 + 4 * l];
        float4 y0 = *(const float4*)&h2s[p][4 * l];
        float4 y1 = *(const float4*)&h2s[p][256 + 4 * l];

        float r1 = dot4(w22a, x0) + dot4(w22b, x1);
        float r2 = dot4(dw22a, x0) + dot4(dw22b, x1);
        float r3 = dot4(u12a, x0) + dot4(u12b, x1);
        float r4 = dot4(du12a, x0) + dot4(du12b, x1);
        float r5 = dot4(u22a, y0) + dot4(u22b, y1);
        float r6 = dot4(du22a, y0) + dot4(du22b, y1);
        r1 = dpp_sum64(r1);
        r2 = dpp_sum64(r2);
        r3 = dpp_sum64(r3);
        r4 = dpp_sum64(r4);
        r5 = dpp_sum64(r5);
        r6 = dpp_sum64(r6);
        float m1 = bcast63(r1), m2 = bcast63(r2), m3 = bcast63(r3);
        float m4 = bcast63(r4), m5 = bcast63(r5), m6 = bcast63(r6);

        // ---- L2 gates at t -> h2(t+1), out[t] ----
        {
            float g0 = cW2[0] * m1 + cdW2[0] * m2 + cU2[0] * m5 + cdU2[0] * m6 + bb2[0];
            float g1 = cW2[1] * m1 + cdW2[1] * m2 + cU2[1] * m5 + cdU2[1] * m6 + bb2[1];
            float g2 = cW2[2] * m1 + cdW2[2] * m2 + cU2[2] * m5 + cdU2[2] * m6 + bb2[2];
            float g3 = cW2[3] * m1 + cdW2[3] * m2 + cU2[3] * m5 + cdU2[3] * m6 + bb2[3];
            float ig = sigm(g0), fg = sigm(g1), gg = tanh_fast(g2), og = sigm(g3);
            c2 = fg * c2 + ig * gg;
            h2v = og * tanh_fast(c2);
            h2s[p ^ 1][tid] = h2v;
            outb[(size_t)t * NH + h] = h2v;  // fire-and-forget (no vmcnt drain)
        }
        // ---- L1 gates at t+1 -> h1(t+2) ----
        if (t < NS - 1) {
            float g0 = cW1[0] * p1 + cdW1[0] * p2 + cU1[0] * m3 + cdU1[0] * m4 + bb1[0];
            float g1 = cW1[1] * p1 + cdW1[1] * p2 + cU1[1] * m3 + cdU1[1] * m4 + bb1[1];
            float g2 = cW1[2] * p1 + cdW1[2] * p2 + cU1[2] * m3 + cdU1[2] * m4 + bb1[2];
            float g3 = cW1[3] * p1 + cdW1[3] * p2 + cU1[3] * m3 + cdU1[3] * m4 + bb1[3];
            float ig = sigm(g0), fg = sigm(g1), gg = tanh_fast(g2), og = sigm(g3);
            c1 = fg * c1 + ig * gg;
            h1v = og * tanh_fast(c1);
            h1s[p ^ 1][tid] = h1v;
        }
        p1 = ppn.x; p2 = ppn.y;
        wg_barrier();  // single barrier: RAW for buf p^1 (WAR-free by dbuf)
    }

    // --- final states: hn (2,B,H) then cn (2,B,H) ---
    float* hn = out + (size_t)NB * NS * NH;
    float* cn = hn + (size_t)2 * NB * NH;
    hn[(size_t)b * NH + h] = h1v;
    hn[(size_t)NB * NH + (size_t)b * NH + h] = h2v;
    cn[(size_t)b * NH + h] = c1;
    cn[(size_t)NB * NH + (size_t)b * NH + h] = c2;
}

extern "C" void kernel_launch(void* const* d_in, const int* in_sizes, int n_in,
                              void* d_out, int out_size, void* d_ws, size_t ws_size,
                              hipStream_t stream) {
    const float* x = (const float*)d_in[0];
    const float* h0 = (const float*)d_in[1];
    const float* c0 = (const float*)d_in[2];
    const float* W11 = (const float*)d_in[3];
    const float* W12 = (const float*)d_in[4];
    const float* U11 = (const float*)d_in[5];
    const float* U12 = (const float*)d_in[6];
    const float* dW11 = (const float*)d_in[7];
    const float* dW12 = (const float*)d_in[8];
    const float* dU11 = (const float*)d_in[9];
    const float* dU12 = (const float*)d_in[10];
    const float* b11 = (const float*)d_in[11];
    const float* b12 = (const float*)d_in[12];
    const float* W21 = (const float*)d_in[13];
    const float* W22 = (const float*)d_in[14];
    const float* U21 = (const float*)d_in[15];
    const float* U22 = (const float*)d_in[16];
    const float* dW21 = (const float*)d_in[17];
    const float* dW22 = (const float*)d_in[18];
    const float* dU21 = (const float*)d_in[19];
    const float* dU22 = (const float*)d_in[20];
    const float* b21 = (const float*)d_in[21];
    const float* b22 = (const float*)d_in[22];

    float* P = (float*)d_ws;  // (B*S, 16) = 2 MB
    float* out = (float*)d_out;

    hipLaunchKernelGGL(precomp_kernel, dim3(NB * NS), dim3(64), 0, stream,
                       x, W12, dW12, P);
    hipLaunchKernelGGL(lstm_kernel, dim3(NB), dim3(512), 0, stream,
                       P, h0, c0,
                       W11, U11, dW11, dU11, U12, dU12, b11, b12,
                       W21, U21, dW21, dU21, W22, dW22, U22, dU22, b21, b22,
                       out);
}

// Round 5
// 703.490 us; speedup vs baseline: 1.5630x; 1.0006x over previous
//
#include <hip/hip_runtime.h>
#include <math.h>

#define NB 64       // batch
#define NS 512      // seq len
#define ND 512      // input dim
#define NH 512      // hidden
// F = 8 factor rows, G = 256

__device__ __forceinline__ float dot4(float4 a, float4 b) {
    return a.x * b.x + a.y * b.y + a.z * b.z + a.w * b.w;
}

// 64-lane sum via DPP (VALU only, no LDS). Total ends in lane 63.
__device__ __forceinline__ float dpp_sum64(float x) {
    x += __int_as_float(__builtin_amdgcn_update_dpp(0, __float_as_int(x), 0x111, 0xf, 0xf, true)); // row_shr:1
    x += __int_as_float(__builtin_amdgcn_update_dpp(0, __float_as_int(x), 0x112, 0xf, 0xf, true)); // row_shr:2
    x += __int_as_float(__builtin_amdgcn_update_dpp(0, __float_as_int(x), 0x114, 0xf, 0xf, true)); // row_shr:4
    x += __int_as_float(__builtin_amdgcn_update_dpp(0, __float_as_int(x), 0x118, 0xf, 0xf, true)); // row_shr:8
    x += __int_as_float(__builtin_amdgcn_update_dpp(0, __float_as_int(x), 0x142, 0xa, 0xf, true)); // row_bcast:15
    x += __int_as_float(__builtin_amdgcn_update_dpp(0, __float_as_int(x), 0x143, 0xc, 0xf, true)); // row_bcast:31
    return x;
}

__device__ __forceinline__ float bcast63(float x) {
    return __int_as_float(__builtin_amdgcn_readlane(__float_as_int(x), 63));
}

__device__ __forceinline__ float sigm(float x) {
    return 1.0f / (1.0f + __expf(-x));
}

__device__ __forceinline__ float tanh_fast(float x) {
    float ax = fabsf(x);
    float e = __expf(2.0f * ax);
    float r = 1.0f - 2.0f / (e + 1.0f);
    return copysignf(r, x);
}

// Workgroup barrier WITHOUT vmcnt drain: own LDS/SMEM ops complete, then
// barrier. Global stores stay in flight across steps.
__device__ __forceinline__ void wg_barrier() {
    asm volatile("s_waitcnt lgkmcnt(0)\n\ts_barrier" ::: "memory");
}

// ---------------------------------------------------------------------------
// Kernel A: P[bt][2f] = (W12 @ x_bt)[f], P[bt][2f+1] = (dW12 @ x_bt)[f]
// (interleaved so the recurrence loads one float2 per factor row)
// ---------------------------------------------------------------------------
__global__ __launch_bounds__(64) void precomp_kernel(
    const float* __restrict__ x, const float* __restrict__ W12,
    const float* __restrict__ dW12, float* __restrict__ P) {
    int bt = blockIdx.x;
    int l = threadIdx.x;  // 0..63
    const float4* xr = (const float4*)(x + (size_t)bt * ND);
    float4 xv0 = xr[l];
    float4 xv1 = xr[64 + l];

    float acc[16];
#pragma unroll
    for (int f = 0; f < 8; ++f) {
        const float4* w = (const float4*)(W12 + f * ND);
        acc[f] = dot4(w[l], xv0) + dot4(w[64 + l], xv1);
        const float4* dw = (const float4*)(dW12 + f * ND);
        acc[8 + f] = dot4(dw[l], xv0) + dot4(dw[64 + l], xv1);
    }
#pragma unroll
    for (int f = 0; f < 16; ++f) acc[f] = dpp_sum64(acc[f]);

    if (l == 63) {
        float4* o = (float4*)(P + (size_t)bt * 16);
        o[0] = make_float4(acc[0], acc[8], acc[1], acc[9]);
        o[1] = make_float4(acc[2], acc[10], acc[3], acc[11]);
        o[2] = make_float4(acc[4], acc[12], acc[5], acc[13]);
        o[3] = make_float4(acc[6], acc[14], acc[7], acc[15]);
    }
}

// ---------------------------------------------------------------------------
// Kernel B: persistent recurrence — one workgroup per batch element.
// 8 waves; wave w owns factor row w and gate rows h = 8*lane + w.
// LDS h-state stored PERMUTED (slot tid = own row) -> stride-1 writes.
// This block's whole P slice (32 KB) is preloaded into LDS, so the main
// loop contains ZERO VMEM loads -> no s_waitcnt vmcnt is ever emitted in
// the loop -> the fire-and-forget output stores never serialize a step.
// ONE lgkm-only barrier per step.
// ---------------------------------------------------------------------------
__global__ __launch_bounds__(512) void lstm_kernel(
    const float* __restrict__ P, const float* __restrict__ h0,
    const float* __restrict__ c0,
    const float* __restrict__ W11, const float* __restrict__ U11,
    const float* __restrict__ dW11, const float* __restrict__ dU11,
    const float* __restrict__ U12, const float* __restrict__ dU12,
    const float* __restrict__ b11, const float* __restrict__ b12,
    const float* __restrict__ W21, const float* __restrict__ U21,
    const float* __restrict__ dW21, const float* __restrict__ dU21,
    const float* __restrict__ W22, const float* __restrict__ dW22,
    const float* __restrict__ U22, const float* __restrict__ dU22,
    const float* __restrict__ b21, const float* __restrict__ b22,
    float* __restrict__ out) {
    int b = blockIdx.x;
    int tid = threadIdx.x;
    int wv = tid >> 6;           // wave = factor row
    int l = tid & 63;            // lane
    int h = 8 * l + wv;          // owned hidden row

    __shared__ float h1s[2][NH];
    __shared__ float h2s[2][NH];
    __shared__ float Ps[NS * 16];  // 32 KB: this block's P slice

    // --- preload P slice into LDS (coalesced, startup only) ---
    {
        const float4* src = (const float4*)(P + (size_t)b * NS * 16);
        float4* dst = (float4*)Ps;
#pragma unroll
        for (int i = 0; i < 4; ++i) dst[tid + i * 512] = src[tid + i * 512];
    }

    // --- permuted gather of the 6 dot-weight vectors (factor row wv) ---
    int kb = 32 * (l & 15) + (l >> 4);
    float4 u12a, u12b, du12a, du12b, w22a, w22b, dw22a, dw22b, u22a, u22b, du22a, du22b;
    {
        const float* M;
#define LOADW(mat, ra, rb)                                              \
        M = (mat) + wv * NH;                                            \
        ra = make_float4(M[kb], M[kb + 8], M[kb + 16], M[kb + 24]);     \
        rb = make_float4(M[kb + 4], M[kb + 12], M[kb + 20], M[kb + 28]);
        LOADW(U12, u12a, u12b)
        LOADW(dU12, du12a, du12b)
        LOADW(W22, w22a, w22b)
        LOADW(dW22, dw22a, dw22b)
        LOADW(U22, u22a, u22b)
        LOADW(dU22, du22a, du22b)
#undef LOADW
    }

    // --- per-thread gate coefficients for owned row h ---
    float cW1[4], cdW1[4], cU1[4], cdU1[4], bb1[4];
    float cW2[4], cdW2[4], cU2[4], cdU2[4], bb2[4];
#pragma unroll
    for (int q = 0; q < 4; ++q) {
        int idx = q * 64 + l;  // (q*512 + h) / 8
        cW1[q] = W11[idx]; cdW1[q] = dW11[idx];
        cU1[q] = U11[idx]; cdU1[q] = dU11[idx];
        bb1[q] = b11[q * NH + h] + b12[q * NH + h];
        cW2[q] = W21[idx]; cdW2[q] = dW21[idx];
        cU2[q] = U21[idx]; cdU2[q] = dU21[idx];
        bb2[q] = b21[q * NH + h] + b22[q * NH + h];
    }

    // --- initial state (slot tid holds exactly h = own row) ---
    float c1 = c0[(size_t)b * NH + h];
    float c2 = c0[(size_t)NB * NH + (size_t)b * NH + h];
    float h1v = h0[(size_t)b * NH + h];
    float h2v = h0[(size_t)NB * NH + (size_t)b * NH + h];
    h1s[0][tid] = h1v;
    h2s[0][tid] = h2v;
    wg_barrier();

    float* outb = out + (size_t)b * NS * NH;

    // ---- prologue: h1(1) from h1(0), x(0) -> h1s[0] ----
    {
        float2 pp = *(const float2*)&Ps[2 * wv];
        float4 x0 = *(const float4*)&h1s[0][4 * l];
        float4 x1 = *(const float4*)&h1s[0][256 + 4 * l];
        float r3 = dot4(u12a, x0) + dot4(u12b, x1);
        float r4 = dot4(du12a, x0) + dot4(du12b, x1);
        float m3 = bcast63(dpp_sum64(r3));
        float m4 = bcast63(dpp_sum64(r4));
        wg_barrier();  // WAR: all reads of h1s[0] done before overwrite
        float g0 = cW1[0] * pp.x + cdW1[0] * pp.y + cU1[0] * m3 + cdU1[0] * m4 + bb1[0];
        float g1 = cW1[1] * pp.x + cdW1[1] * pp.y + cU1[1] * m3 + cdU1[1] * m4 + bb1[1];
        float g2 = cW1[2] * pp.x + cdW1[2] * pp.y + cU1[2] * m3 + cdU1[2] * m4 + bb1[2];
        float g3 = cW1[3] * pp.x + cdW1[3] * pp.y + cU1[3] * m3 + cdU1[3] * m4 + bb1[3];
        float ig = sigm(g0), fg = sigm(g1), gg = tanh_fast(g2), og = sigm(g3);
        c1 = fg * c1 + ig * gg;
        h1v = og * tanh_fast(c1);
        h1s[0][tid] = h1v;
        wg_barrier();  // RAW
    }

    // P prefetch for iter 0's L1 gates (step t+1 = 1)
    float p1, p2;
    {
        float2 pp = *(const float2*)&Ps[16 + 2 * wv];
        p1 = pp.x; p2 = pp.y;
    }

    // ---- steady state: at top of iter t, buf p=t&1 holds h1(t+1), h2(t) ----
    for (int t = 0; t < NS; ++t) {
        const int p = t & 1;
        // prefetch P for next iteration's L1 gates (step t+2) — LDS, no VMEM
        int tn = (t + 2 < NS) ? t + 2 : NS - 1;
        float2 ppn = *(const float2*)&Ps[tn * 16 + 2 * wv];

        float4 x0 = *(const float4*)&h1s[p][4 * l];
        float4 x1 = *(const float4*)&h1s[p][256 + 4 * l];
        float4 y0 = *(const float4*)&h2s[p][4 * l];
        float4 y1 = *(const float4*)&h2s[p][256 + 4 * l];

        float r1 = dot4(w22a, x0) + dot4(w22b, x1);
        float r2 = dot4(dw22a, x0) + dot4(dw22b, x1);
        float r3 = dot4(u12a, x0) + dot4(u12b, x1);
        float r4 = dot4(du12a, x0) + dot4(du12b, x1);
        float r5 = dot4(u22a, y0) + dot4(u22b, y1);
        float r6 = dot4(du22a, y0) + dot4(du22b, y1);
        r1 = dpp_sum64(r1);
        r2 = dpp_sum64(r2);
        r3 = dpp_sum64(r3);
        r4 = dpp_sum64(r4);
        r5 = dpp_sum64(r5);
        r6 = dpp_sum64(r6);
        float m1 = bcast63(r1), m2 = bcast63(r2), m3 = bcast63(r3);
        float m4 = bcast63(r4), m5 = bcast63(r5), m6 = bcast63(r6);

        // ---- L2 gates at t -> h2(t+1), out[t] ----
        {
            float g0 = cW2[0] * m1 + cdW2[0] * m2 + cU2[0] * m5 + cdU2[0] * m6 + bb2[0];
            float g1 = cW2[1] * m1 + cdW2[1] * m2 + cU2[1] * m5 + cdU2[1] * m6 + bb2[1];
            float g2 = cW2[2] * m1 + cdW2[2] * m2 + cU2[2] * m5 + cdU2[2] * m6 + bb2[2];
            float g3 = cW2[3] * m1 + cdW2[3] * m2 + cU2[3] * m5 + cdU2[3] * m6 + bb2[3];
            float ig = sigm(g0), fg = sigm(g1), gg = tanh_fast(g2), og = sigm(g3);
            c2 = fg * c2 + ig * gg;
            h2v = og * tanh_fast(c2);
            h2s[p ^ 1][tid] = h2v;
            outb[(size_t)t * NH + h] = h2v;  // fire-and-forget, never waited
        }
        // ---- L1 gates at t+1 -> h1(t+2) ----
        if (t < NS - 1) {
            float g0 = cW1[0] * p1 + cdW1[0] * p2 + cU1[0] * m3 + cdU1[0] * m4 + bb1[0];
            float g1 = cW1[1] * p1 + cdW1[1] * p2 + cU1[1] * m3 + cdU1[1] * m4 + bb1[1];
            float g2 = cW1[2] * p1 + cdW1[2] * p2 + cU1[2] * m3 + cdU1[2] * m4 + bb1[2];
            float g3 = cW1[3] * p1 + cdW1[3] * p2 + cU1[3] * m3 + cdU1[3] * m4 + bb1[3];
            float ig = sigm(g0), fg = sigm(g1), gg = tanh_fast(g2), og = sigm(g3);
            c1 = fg * c1 + ig * gg;
            h1v = og * tanh_fast(c1);
            h1s[p ^ 1][tid] = h1v;
        }
        p1 = ppn.x; p2 = ppn.y;
        wg_barrier();  // single barrier: RAW for buf p^1 (WAR-free by dbuf)
    }

    // --- final states: hn (2,B,H) then cn (2,B,H) ---
    float* hn = out + (size_t)NB * NS * NH;
    float* cn = hn + (size_t)2 * NB * NH;
    hn[(size_t)b * NH + h] = h1v;
    hn[(size_t)NB * NH + (size_t)b * NH + h] = h2v;
    cn[(size_t)b * NH + h] = c1;
    cn[(size_t)NB * NH + (size_t)b * NH + h] = c2;
}

extern "C" void kernel_launch(void* const* d_in, const int* in_sizes, int n_in,
                              void* d_out, int out_size, void* d_ws, size_t ws_size,
                              hipStream_t stream) {
    const float* x = (const float*)d_in[0];
    const float* h0 = (const float*)d_in[1];
    const float* c0 = (const float*)d_in[2];
    const float* W11 = (const float*)d_in[3];
    const float* W12 = (const float*)d_in[4];
    const float* U11 = (const float*)d_in[5];
    const float* U12 = (const float*)d_in[6];
    const float* dW11 = (const float*)d_in[7];
    const float* dW12 = (const float*)d_in[8];
    const float* dU11 = (const float*)d_in[9];
    const float* dU12 = (const float*)d_in[10];
    const float* b11 = (const float*)d_in[11];
    const float* b12 = (const float*)d_in[12];
    const float* W21 = (const float*)d_in[13];
    const float* W22 = (const float*)d_in[14];
    const float* U21 = (const float*)d_in[15];
    const float* U22 = (const float*)d_in[16];
    const float* dW21 = (const float*)d_in[17];
    const float* dW22 = (const float*)d_in[18];
    const float* dU21 = (const float*)d_in[19];
    const float* dU22 = (const float*)d_in[20];
    const float* b21 = (const float*)d_in[21];
    const float* b22 = (const float*)d_in[22];

    float* P = (float*)d_ws;  // (B*S, 16) = 2 MB
    float* out = (float*)d_out;

    hipLaunchKernelGGL(precomp_kernel, dim3(NB * NS), dim3(64), 0, stream,
                       x, W12, dW12, P);
    hipLaunchKernelGGL(lstm_kernel, dim3(NB), dim3(512), 0, stream,
                       P, h0, c0,
                       W11, U11, dW11, dU11, U12, dU12, b11, b12,
                       W21, U21, dW21, dU21, W22, dW22, U22, dU22, b21, b22,
                       out);
}

// Round 6
// 699.504 us; speedup vs baseline: 1.5719x; 1.0057x over previous
//
#include <hip/hip_runtime.h>
#include <math.h>

#define NB 64       // batch
#define NS 512      // seq len
#define ND 512      // input dim
#define NH 512      // hidden
// F = 8 factor rows, G = 256

// Opaque register pin: forces the value to be materialized in a VGPR and
// prevents the compiler from rematerializing it via a memory load inside
// the loop (the VGPR_Count=64 symptom: weights were re-loaded from L2
// every timestep). Emits zero instructions.
#define PIN(x) asm volatile("" : "+v"(x))
#define PIN4(v) do { PIN(v.x); PIN(v.y); PIN(v.z); PIN(v.w); } while (0)

__device__ __forceinline__ float dot4(float4 a, float4 b) {
    return a.x * b.x + a.y * b.y + a.z * b.z + a.w * b.w;
}

// 64-lane sum via DPP (VALU only, no LDS). Total ends in lane 63.
__device__ __forceinline__ float dpp_sum64(float x) {
    x += __int_as_float(__builtin_amdgcn_update_dpp(0, __float_as_int(x), 0x111, 0xf, 0xf, true)); // row_shr:1
    x += __int_as_float(__builtin_amdgcn_update_dpp(0, __float_as_int(x), 0x112, 0xf, 0xf, true)); // row_shr:2
    x += __int_as_float(__builtin_amdgcn_update_dpp(0, __float_as_int(x), 0x114, 0xf, 0xf, true)); // row_shr:4
    x += __int_as_float(__builtin_amdgcn_update_dpp(0, __float_as_int(x), 0x118, 0xf, 0xf, true)); // row_shr:8
    x += __int_as_float(__builtin_amdgcn_update_dpp(0, __float_as_int(x), 0x142, 0xa, 0xf, true)); // row_bcast:15
    x += __int_as_float(__builtin_amdgcn_update_dpp(0, __float_as_int(x), 0x143, 0xc, 0xf, true)); // row_bcast:31
    return x;
}

__device__ __forceinline__ float bcast63(float x) {
    return __int_as_float(__builtin_amdgcn_readlane(__float_as_int(x), 63));
}

__device__ __forceinline__ float sigm(float x) {
    return 1.0f / (1.0f + __expf(-x));
}

__device__ __forceinline__ float tanh_fast(float x) {
    float ax = fabsf(x);
    float e = __expf(2.0f * ax);
    float r = 1.0f - 2.0f / (e + 1.0f);
    return copysignf(r, x);
}

// Workgroup barrier WITHOUT vmcnt drain: own LDS ops complete, then barrier.
// Global stores stay in flight across steps.
__device__ __forceinline__ void wg_barrier() {
    asm volatile("s_waitcnt lgkmcnt(0)\n\ts_barrier" ::: "memory");
}

// ---------------------------------------------------------------------------
// Kernel A: P[bt][2f] = (W12 @ x_bt)[f], P[bt][2f+1] = (dW12 @ x_bt)[f]
// ---------------------------------------------------------------------------
__global__ __launch_bounds__(64) void precomp_kernel(
    const float* __restrict__ x, const float* __restrict__ W12,
    const float* __restrict__ dW12, float* __restrict__ P) {
    int bt = blockIdx.x;
    int l = threadIdx.x;  // 0..63
    const float4* xr = (const float4*)(x + (size_t)bt * ND);
    float4 xv0 = xr[l];
    float4 xv1 = xr[64 + l];

    float acc[16];
#pragma unroll
    for (int f = 0; f < 8; ++f) {
        const float4* w = (const float4*)(W12 + f * ND);
        acc[f] = dot4(w[l], xv0) + dot4(w[64 + l], xv1);
        const float4* dw = (const float4*)(dW12 + f * ND);
        acc[8 + f] = dot4(dw[l], xv0) + dot4(dw[64 + l], xv1);
    }
#pragma unroll
    for (int f = 0; f < 16; ++f) acc[f] = dpp_sum64(acc[f]);

    if (l == 63) {
        float4* o = (float4*)(P + (size_t)bt * 16);
        o[0] = make_float4(acc[0], acc[8], acc[1], acc[9]);
        o[1] = make_float4(acc[2], acc[10], acc[3], acc[11]);
        o[2] = make_float4(acc[4], acc[12], acc[5], acc[13]);
        o[3] = make_float4(acc[6], acc[14], acc[7], acc[15]);
    }
}

// ---------------------------------------------------------------------------
// Kernel B: persistent recurrence — one workgroup per batch element.
// 8 waves; wave w owns factor row w and gate rows h = 8*lane + w.
// LDS h-state stored PERMUTED (slot tid = own row) -> stride-1 writes.
// P slice preloaded to LDS; weights/coefs PINNED in VGPRs (launch_bounds
// (512,2) gives the 256-VGPR budget) so the loop has ZERO VMEM loads.
// ONE lgkm-only barrier per step; output stores fire-and-forget.
// ---------------------------------------------------------------------------
__global__ __launch_bounds__(512, 2) void lstm_kernel(
    const float* __restrict__ P, const float* __restrict__ h0,
    const float* __restrict__ c0,
    const float* __restrict__ W11, const float* __restrict__ U11,
    const float* __restrict__ dW11, const float* __restrict__ dU11,
    const float* __restrict__ U12, const float* __restrict__ dU12,
    const float* __restrict__ b11, const float* __restrict__ b12,
    const float* __restrict__ W21, const float* __restrict__ U21,
    const float* __restrict__ dW21, const float* __restrict__ dU21,
    const float* __restrict__ W22, const float* __restrict__ dW22,
    const float* __restrict__ U22, const float* __restrict__ dU22,
    const float* __restrict__ b21, const float* __restrict__ b22,
    float* __restrict__ out) {
    int b = blockIdx.x;
    int tid = threadIdx.x;
    int wv = tid >> 6;           // wave = factor row
    int l = tid & 63;            // lane
    int h = 8 * l + wv;          // owned hidden row

    __shared__ float h1s[2][NH];
    __shared__ float h2s[2][NH];
    __shared__ float Ps[NS * 16];  // 32 KB: this block's P slice

    // --- preload P slice into LDS (coalesced, startup only) ---
    {
        const float4* src = (const float4*)(P + (size_t)b * NS * 16);
        float4* dst = (float4*)Ps;
#pragma unroll
        for (int i = 0; i < 4; ++i) dst[tid + i * 512] = src[tid + i * 512];
    }

    // --- permuted gather of the 6 dot-weight vectors (factor row wv) ---
    int kb = 32 * (l & 15) + (l >> 4);
    float4 u12a, u12b, du12a, du12b, w22a, w22b, dw22a, dw22b, u22a, u22b, du22a, du22b;
    {
        const float* M;
#define LOADW(mat, ra, rb)                                              \
        M = (mat) + wv * NH;                                            \
        ra = make_float4(M[kb], M[kb + 8], M[kb + 16], M[kb + 24]);     \
        rb = make_float4(M[kb + 4], M[kb + 12], M[kb + 20], M[kb + 28]);
        LOADW(U12, u12a, u12b)
        LOADW(dU12, du12a, du12b)
        LOADW(W22, w22a, w22b)
        LOADW(dW22, dw22a, dw22b)
        LOADW(U22, u22a, u22b)
        LOADW(dU22, du22a, du22b)
#undef LOADW
        PIN4(u12a); PIN4(u12b); PIN4(du12a); PIN4(du12b);
        PIN4(w22a); PIN4(w22b); PIN4(dw22a); PIN4(dw22b);
        PIN4(u22a); PIN4(u22b); PIN4(du22a); PIN4(du22b);
    }

    // --- per-thread gate coefficients for owned row h ---
    float cW1[4], cdW1[4], cU1[4], cdU1[4], bb1[4];
    float cW2[4], cdW2[4], cU2[4], cdU2[4], bb2[4];
#pragma unroll
    for (int q = 0; q < 4; ++q) {
        int idx = q * 64 + l;  // (q*512 + h) / 8
        cW1[q] = W11[idx]; cdW1[q] = dW11[idx];
        cU1[q] = U11[idx]; cdU1[q] = dU11[idx];
        bb1[q] = b11[q * NH + h] + b12[q * NH + h];
        cW2[q] = W21[idx]; cdW2[q] = dW21[idx];
        cU2[q] = U21[idx]; cdU2[q] = dU21[idx];
        bb2[q] = b21[q * NH + h] + b22[q * NH + h];
        PIN(cW1[q]); PIN(cdW1[q]); PIN(cU1[q]); PIN(cdU1[q]); PIN(bb1[q]);
        PIN(cW2[q]); PIN(cdW2[q]); PIN(cU2[q]); PIN(cdU2[q]); PIN(bb2[q]);
    }

    // --- initial state (slot tid holds exactly h = own row) ---
    float c1 = c0[(size_t)b * NH + h];
    float c2 = c0[(size_t)NB * NH + (size_t)b * NH + h];
    float h1v = h0[(size_t)b * NH + h];
    float h2v = h0[(size_t)NB * NH + (size_t)b * NH + h];
    h1s[0][tid] = h1v;
    h2s[0][tid] = h2v;
    wg_barrier();

    float* outb = out + (size_t)b * NS * NH;

    // ---- prologue: h1(1) from h1(0), x(0) -> h1s[0] ----
    {
        float2 pp = *(const float2*)&Ps[2 * wv];
        float4 x0 = *(const float4*)&h1s[0][4 * l];
        float4 x1 = *(const float4*)&h1s[0][256 + 4 * l];
        float r3 = dot4(u12a, x0) + dot4(u12b, x1);
        float r4 = dot4(du12a, x0) + dot4(du12b, x1);
        float m3 = bcast63(dpp_sum64(r3));
        float m4 = bcast63(dpp_sum64(r4));
        wg_barrier();  // WAR: all reads of h1s[0] done before overwrite
        float g0 = cW1[0] * pp.x + cdW1[0] * pp.y + cU1[0] * m3 + cdU1[0] * m4 + bb1[0];
        float g1 = cW1[1] * pp.x + cdW1[1] * pp.y + cU1[1] * m3 + cdU1[1] * m4 + bb1[1];
        float g2 = cW1[2] * pp.x + cdW1[2] * pp.y + cU1[2] * m3 + cdU1[2] * m4 + bb1[2];
        float g3 = cW1[3] * pp.x + cdW1[3] * pp.y + cU1[3] * m3 + cdU1[3] * m4 + bb1[3];
        float ig = sigm(g0), fg = sigm(g1), gg = tanh_fast(g2), og = sigm(g3);
        c1 = fg * c1 + ig * gg;
        h1v = og * tanh_fast(c1);
        h1s[0][tid] = h1v;
        wg_barrier();  // RAW
    }

    // P prefetch for iter 0's L1 gates (step t+1 = 1)
    float p1, p2;
    {
        float2 pp = *(const float2*)&Ps[16 + 2 * wv];
        p1 = pp.x; p2 = pp.y;
    }

    // ---- steady state: at top of iter t, buf p=t&1 holds h1(t+1), h2(t) ----
    for (int t = 0; t < NS; ++t) {
        const int p = t & 1;
        // prefetch P for next iteration's L1 gates (step t+2) — LDS, no VMEM
        int tn = (t + 2 < NS) ? t + 2 : NS - 1;
        float2 ppn = *(const float2*)&Ps[tn * 16 + 2 * wv];

        float4 x0 = *(const float4*)&h1s[p][4 * l];
        float4 x1 = *(const float4*)&h1s[p][256 + 4 * l];
        float4 y0 = *(const float4*)&h2s[p][4 * l];
        float4 y1 = *(const float4*)&h2s[p][256 + 4 * l];

        float r1 = dot4(w22a, x0) + dot4(w22b, x1);
        float r2 = dot4(dw22a, x0) + dot4(dw22b, x1);
        float r3 = dot4(u12a, x0) + dot4(u12b, x1);
        float r4 = dot4(du12a, x0) + dot4(du12b, x1);
        float r5 = dot4(u22a, y0) + dot4(u22b, y1);
        float r6 = dot4(du22a, y0) + dot4(du22b, y1);
        r1 = dpp_sum64(r1);
        r2 = dpp_sum64(r2);
        r3 = dpp_sum64(r3);
        r4 = dpp_sum64(r4);
        r5 = dpp_sum64(r5);
        r6 = dpp_sum64(r6);
        float m1 = bcast63(r1), m2 = bcast63(r2), m3 = bcast63(r3);
        float m4 = bcast63(r4), m5 = bcast63(r5), m6 = bcast63(r6);

        // ---- L2 gates at t -> h2(t+1), out[t] ----
        {
            float g0 = cW2[0] * m1 + cdW2[0] * m2 + cU2[0] * m5 + cdU2[0] * m6 + bb2[0];
            float g1 = cW2[1] * m1 + cdW2[1] * m2 + cU2[1] * m5 + cdU2[1] * m6 + bb2[1];
            float g2 = cW2[2] * m1 + cdW2[2] * m2 + cU2[2] * m5 + cdU2[2] * m6 + bb2[2];
            float g3 = cW2[3] * m1 + cdW2[3] * m2 + cU2[3] * m5 + cdU2[3] * m6 + bb2[3];
            float ig = sigm(g0), fg = sigm(g1), gg = tanh_fast(g2), og = sigm(g3);
            c2 = fg * c2 + ig * gg;
            h2v = og * tanh_fast(c2);
            h2s[p ^ 1][tid] = h2v;
            outb[(size_t)t * NH + h] = h2v;  // fire-and-forget, never waited
        }
        // ---- L1 gates at t+1 -> h1(t+2) ----
        if (t < NS - 1) {
            float g0 = cW1[0] * p1 + cdW1[0] * p2 + cU1[0] * m3 + cdU1[0] * m4 + bb1[0];
            float g1 = cW1[1] * p1 + cdW1[1] * p2 + cU1[1] * m3 + cdU1[1] * m4 + bb1[1];
            float g2 = cW1[2] * p1 + cdW1[2] * p2 + cU1[2] * m3 + cdU1[2] * m4 + bb1[2];
            float g3 = cW1[3] * p1 + cdW1[3] * p2 + cU1[3] * m3 + cdU1[3] * m4 + bb1[3];
            float ig = sigm(g0), fg = sigm(g1), gg = tanh_fast(g2), og = sigm(g3);
            c1 = fg * c1 + ig * gg;
            h1v = og * tanh_fast(c1);
            h1s[p ^ 1][tid] = h1v;
        }
        p1 = ppn.x; p2 = ppn.y;
        wg_barrier();  // single barrier: RAW for buf p^1 (WAR-free by dbuf)
    }

    // --- final states: hn (2,B,H) then cn (2,B,H) ---
    float* hn = out + (size_t)NB * NS * NH;
    float* cn = hn + (size_t)2 * NB * NH;
    hn[(size_t)b * NH + h] = h1v;
    hn[(size_t)NB * NH + (size_t)b * NH + h] = h2v;
    cn[(size_t)b * NH + h] = c1;
    cn[(size_t)NB * NH + (size_t)b * NH + h] = c2;
}

extern "C" void kernel_launch(void* const* d_in, const int* in_sizes, int n_in,
                              void* d_out, int out_size, void* d_ws, size_t ws_size,
                              hipStream_t stream) {
    const float* x = (const float*)d_in[0];
    const float* h0 = (const float*)d_in[1];
    const float* c0 = (const float*)d_in[2];
    const float* W11 = (const float*)d_in[3];
    const float* W12 = (const float*)d_in[4];
    const float* U11 = (const float*)d_in[5];
    const float* U12 = (const float*)d_in[6];
    const float* dW11 = (const float*)d_in[7];
    const float* dW12 = (const float*)d_in[8];
    const float* dU11 = (const float*)d_in[9];
    const float* dU12 = (const float*)d_in[10];
    const float* b11 = (const float*)d_in[11];
    const float* b12 = (const float*)d_in[12];
    const float* W21 = (const float*)d_in[13];
    const float* W22 = (const float*)d_in[14];
    const float* U21 = (const float*)d_in[15];
    const float* U22 = (const float*)d_in[16];
    const float* dW21 = (const float*)d_in[17];
    const float* dW22 = (const float*)d_in[18];
    const float* dU21 = (const float*)d_in[19];
    const float* dU22 = (const float*)d_in[20];
    const float* b21 = (const float*)d_in[21];
    const float* b22 = (const float*)d_in[22];

    float* P = (float*)d_ws;  // (B*S, 16) = 2 MB
    float* out = (float*)d_out;

    hipLaunchKernelGGL(precomp_kernel, dim3(NB * NS), dim3(64), 0, stream,
                       x, W12, dW12, P);
    hipLaunchKernelGGL(lstm_kernel, dim3(NB), dim3(512), 0, stream,
                       P, h0, c0,
                       W11, U11, dW11, dU11, U12, dU12, b11, b12,
                       W21, U21, dW21, dU21, W22, dW22, U22, dU22, b21, b22,
                       out);
}

// Round 7
// 550.216 us; speedup vs baseline: 1.9984x; 1.2713x over previous
//
#include <hip/hip_runtime.h>
#include <math.h>

#define NB 64       // batch
#define NS 512      // seq len
#define ND 512      // input dim
#define NH 512      // hidden
// F = 8 factor rows, G = 256

__device__ __forceinline__ float dot8(float4 a0, float4 a1, float4 x0, float4 x1) {
    float s = a0.x * x0.x;
    s = fmaf(a0.y, x0.y, s); s = fmaf(a0.z, x0.z, s); s = fmaf(a0.w, x0.w, s);
    s = fmaf(a1.x, x1.x, s); s = fmaf(a1.y, x1.y, s); s = fmaf(a1.z, x1.z, s);
    s = fmaf(a1.w, x1.w, s);
    return s;
}

// 64-lane sum via DPP (VALU only, no LDS). Total ends in lane 63.
__device__ __forceinline__ float dpp_sum64(float x) {
    x += __int_as_float(__builtin_amdgcn_update_dpp(0, __float_as_int(x), 0x111, 0xf, 0xf, true)); // row_shr:1
    x += __int_as_float(__builtin_amdgcn_update_dpp(0, __float_as_int(x), 0x112, 0xf, 0xf, true)); // row_shr:2
    x += __int_as_float(__builtin_amdgcn_update_dpp(0, __float_as_int(x), 0x114, 0xf, 0xf, true)); // row_shr:4
    x += __int_as_float(__builtin_amdgcn_update_dpp(0, __float_as_int(x), 0x118, 0xf, 0xf, true)); // row_shr:8
    x += __int_as_float(__builtin_amdgcn_update_dpp(0, __float_as_int(x), 0x142, 0xa, 0xf, true)); // row_bcast:15
    x += __int_as_float(__builtin_amdgcn_update_dpp(0, __float_as_int(x), 0x143, 0xc, 0xf, true)); // row_bcast:31
    return x;
}

__device__ __forceinline__ float bcast63(float x) {
    return __int_as_float(__builtin_amdgcn_readlane(__float_as_int(x), 63));
}

__device__ __forceinline__ float sigm(float x) {
    return 1.0f / (1.0f + __expf(-x));
}

__device__ __forceinline__ float tanh_fast(float x) {
    float ax = fabsf(x);
    float e = __expf(2.0f * ax);
    float r = 1.0f - 2.0f / (e + 1.0f);
    return copysignf(r, x);
}

// lgkm-only barrier: global stores stay in flight across steps.
__device__ __forceinline__ void wg_barrier() {
    asm volatile("s_waitcnt lgkmcnt(0)\n\ts_barrier" ::: "memory");
}
// full-drain barrier: all waves' VMEM stores retired before anyone passes.
__device__ __forceinline__ void full_barrier() {
    asm volatile("s_waitcnt vmcnt(0) lgkmcnt(0)\n\ts_barrier" ::: "memory");
}

// ---------------------------------------------------------------------------
// Kernel A: P[bt][2f] = (W12 @ x_bt)[f], P[bt][2f+1] = (dW12 @ x_bt)[f]
// ---------------------------------------------------------------------------
__global__ __launch_bounds__(64) void precomp_kernel(
    const float* __restrict__ x, const float* __restrict__ W12,
    const float* __restrict__ dW12, float* __restrict__ P) {
    int bt = blockIdx.x;
    int l = threadIdx.x;  // 0..63
    const float4* xr = (const float4*)(x + (size_t)bt * ND);
    float4 xv0 = xr[l];
    float4 xv1 = xr[64 + l];

    float acc[16];
#pragma unroll
    for (int f = 0; f < 8; ++f) {
        const float4* w = (const float4*)(W12 + f * ND);
        acc[f] = dot8(w[l], w[64 + l], xv0, xv1);
        const float4* dw = (const float4*)(dW12 + f * ND);
        acc[8 + f] = dot8(dw[l], dw[64 + l], xv0, xv1);
    }
#pragma unroll
    for (int f = 0; f < 16; ++f) acc[f] = dpp_sum64(acc[f]);

    if (l == 63) {
        float4* o = (float4*)(P + (size_t)bt * 16);
        o[0] = make_float4(acc[0], acc[8], acc[1], acc[9]);
        o[1] = make_float4(acc[2], acc[10], acc[3], acc[11]);
        o[2] = make_float4(acc[4], acc[12], acc[5], acc[13]);
        o[3] = make_float4(acc[6], acc[14], acc[7], acc[15]);
    }
}

// ---------------------------------------------------------------------------
// Kernel B: 2-stage pipeline, 2 blocks per batch element (128 blocks).
// role 0 (bid<64): layer-1 recurrence + W22/dW22 projections -> mval,flags
// role 1 (bid>=64): layer-2 recurrence consuming mval -> out
// Flags batched every 8 steps; release via full-drain barrier + atomic store,
// acquire via __hip_atomic_load (L1-invalidating) once per 8 steps.
// ---------------------------------------------------------------------------
__global__ __launch_bounds__(512) void lstm_pipe_kernel(
    const float* __restrict__ P, const float* __restrict__ h0,
    const float* __restrict__ c0,
    const float* __restrict__ W11, const float* __restrict__ U11,
    const float* __restrict__ dW11, const float* __restrict__ dU11,
    const float* __restrict__ U12, const float* __restrict__ dU12,
    const float* __restrict__ b11, const float* __restrict__ b12,
    const float* __restrict__ W21, const float* __restrict__ U21,
    const float* __restrict__ dW21, const float* __restrict__ dU21,
    const float* __restrict__ W22, const float* __restrict__ dW22,
    const float* __restrict__ U22, const float* __restrict__ dU22,
    const float* __restrict__ b21, const float* __restrict__ b22,
    float* __restrict__ mval, unsigned int* __restrict__ flagb,
    float* __restrict__ out) {
    int role = blockIdx.x >> 6;   // 0 = producer (L1), 1 = consumer (L2)
    int b = blockIdx.x & 63;
    int tid = threadIdx.x;
    int wv = tid >> 6;            // wave = factor row
    int l = tid & 63;             // lane
    int h = 8 * l + wv;           // owned hidden row

    __shared__ float Ps[NS * 16];   // 32 KB (producer only)
    __shared__ float hs[2][NH];     // 4 KB state double-buffer

    int kb = 32 * (l & 15) + (l >> 4);  // permuted weight gather base
    float* hn = out + (size_t)NB * NS * NH;
    float* cn = hn + (size_t)2 * NB * NH;

    if (role == 0) {
        // =================== PRODUCER: layer 1 ===================
        // preload P slice into LDS
        {
            const float4* src = (const float4*)(P + (size_t)b * NS * 16);
            float4* dst = (float4*)Ps;
#pragma unroll
            for (int i = 0; i < 4; ++i) dst[tid + i * 512] = src[tid + i * 512];
        }
        float4 u12a, u12b, du12a, du12b, w22a, w22b, dw22a, dw22b;
        {
            const float* M;
#define LOADW(mat, ra, rb)                                              \
            M = (mat) + wv * NH;                                        \
            ra = make_float4(M[kb], M[kb + 8], M[kb + 16], M[kb + 24]); \
            rb = make_float4(M[kb + 4], M[kb + 12], M[kb + 20], M[kb + 28]);
            LOADW(U12, u12a, u12b)
            LOADW(dU12, du12a, du12b)
            LOADW(W22, w22a, w22b)
            LOADW(dW22, dw22a, dw22b)
        }
        float cW1[4], cdW1[4], cU1[4], cdU1[4], bb1[4];
#pragma unroll
        for (int q = 0; q < 4; ++q) {
            int idx = q * 64 + l;
            cW1[q] = W11[idx]; cdW1[q] = dW11[idx];
            cU1[q] = U11[idx]; cdU1[q] = dU11[idx];
            bb1[q] = b11[q * NH + h] + b12[q * NH + h];
        }
        float c1 = c0[(size_t)b * NH + h];
        float h1v = h0[(size_t)b * NH + h];
        hs[0][tid] = h1v;
        wg_barrier();

        // prologue: h1(1) from h1(0), x(0)
        {
            float2 pp = *(const float2*)&Ps[2 * wv];
            float4 x0 = *(const float4*)&hs[0][4 * l];
            float4 x1 = *(const float4*)&hs[0][256 + 4 * l];
            float r3 = dot8(u12a, u12b, x0, x1);
            float r4 = dot8(du12a, du12b, x0, x1);
            float m3 = bcast63(dpp_sum64(r3));
            float m4 = bcast63(dpp_sum64(r4));
            wg_barrier();
            float g0 = cW1[0] * pp.x + cdW1[0] * pp.y + cU1[0] * m3 + cdU1[0] * m4 + bb1[0];
            float g1 = cW1[1] * pp.x + cdW1[1] * pp.y + cU1[1] * m3 + cdU1[1] * m4 + bb1[1];
            float g2 = cW1[2] * pp.x + cdW1[2] * pp.y + cU1[2] * m3 + cdU1[2] * m4 + bb1[2];
            float g3 = cW1[3] * pp.x + cdW1[3] * pp.y + cU1[3] * m3 + cdU1[3] * m4 + bb1[3];
            float ig = sigm(g0), fg = sigm(g1), gg = tanh_fast(g2), og = sigm(g3);
            c1 = fg * c1 + ig * gg;
            h1v = og * tanh_fast(c1);
            hs[0][tid] = h1v;
            wg_barrier();
        }
        float p1, p2;
        {
            float2 pp = *(const float2*)&Ps[16 + 2 * wv];
            p1 = pp.x; p2 = pp.y;
        }
        float* mvb = mval + (size_t)b * NS * 16;
        unsigned int* fbb = flagb + b * (NS / 8);

        for (int t = 0; t < NS; ++t) {
            // publish batch flag: data for steps [t-8, t-1] drained by the
            // full barrier at end of iter t-1 (t&7==0 path).
            if ((t & 7) == 0 && t > 0 && tid == 0)
                __hip_atomic_store(&fbb[(t >> 3) - 1], 1u,
                                   __ATOMIC_RELEASE, __HIP_MEMORY_SCOPE_AGENT);
            const int p = t & 1;
            int tn = (t + 2 < NS) ? t + 2 : NS - 1;
            float2 ppn = *(const float2*)&Ps[tn * 16 + 2 * wv];

            float4 x0 = *(const float4*)&hs[p][4 * l];
            float4 x1 = *(const float4*)&hs[p][256 + 4 * l];
            float r1 = dot8(w22a, w22b, x0, x1);
            float r2 = dot8(dw22a, dw22b, x0, x1);
            float r3 = dot8(u12a, u12b, x0, x1);
            float r4 = dot8(du12a, du12b, x0, x1);
            r1 = dpp_sum64(r1); r2 = dpp_sum64(r2);
            r3 = dpp_sum64(r3); r4 = dpp_sum64(r4);
            float m1 = bcast63(r1), m2 = bcast63(r2);
            float m3 = bcast63(r3), m4 = bcast63(r4);
            if (l == 63) *(float2*)&mvb[t * 16 + 2 * wv] = make_float2(m1, m2);

            if (t < NS - 1) {
                float g0 = cW1[0] * p1 + cdW1[0] * p2 + cU1[0] * m3 + cdU1[0] * m4 + bb1[0];
                float g1 = cW1[1] * p1 + cdW1[1] * p2 + cU1[1] * m3 + cdU1[1] * m4 + bb1[1];
                float g2 = cW1[2] * p1 + cdW1[2] * p2 + cU1[2] * m3 + cdU1[2] * m4 + bb1[2];
                float g3 = cW1[3] * p1 + cdW1[3] * p2 + cU1[3] * m3 + cdU1[3] * m4 + bb1[3];
                float ig = sigm(g0), fg = sigm(g1), gg = tanh_fast(g2), og = sigm(g3);
                c1 = fg * c1 + ig * gg;
                h1v = og * tanh_fast(c1);
                hs[p ^ 1][tid] = h1v;
            }
            p1 = ppn.x; p2 = ppn.y;
            if ((t & 7) == 7) full_barrier(); else wg_barrier();
        }
        if (tid == 0)
            __hip_atomic_store(&fbb[(NS / 8) - 1], 1u,
                               __ATOMIC_RELEASE, __HIP_MEMORY_SCOPE_AGENT);
        hn[(size_t)b * NH + h] = h1v;
        cn[(size_t)b * NH + h] = c1;
    } else {
        // =================== CONSUMER: layer 2 ===================
        float4 u22a, u22b, du22a, du22b;
        {
            const float* M;
            LOADW(U22, u22a, u22b)
            LOADW(dU22, du22a, du22b)
#undef LOADW
        }
        float cW2[4], cdW2[4], cU2[4], cdU2[4], bb2[4];
#pragma unroll
        for (int q = 0; q < 4; ++q) {
            int idx = q * 64 + l;
            cW2[q] = W21[idx]; cdW2[q] = dW21[idx];
            cU2[q] = U21[idx]; cdU2[q] = dU21[idx];
            bb2[q] = b21[q * NH + h] + b22[q * NH + h];
        }
        float c2 = c0[(size_t)NB * NH + (size_t)b * NH + h];
        float h2v = h0[(size_t)NB * NH + (size_t)b * NH + h];
        hs[0][tid] = h2v;
        wg_barrier();

        const float* mvb = mval + (size_t)b * NS * 16;
        const unsigned int* fbb = flagb + b * (NS / 8);
        float* outb = out + (size_t)b * NS * NH;
        float2 mm = make_float2(0.f, 0.f), mmn = mm;

        for (int t = 0; t < NS; ++t) {
            const int p = t & 1;
            if ((t & 7) == 0) {
                // one acquire per 8 steps validates records t..t+7
                while (__hip_atomic_load(&fbb[t >> 3], __ATOMIC_ACQUIRE,
                                         __HIP_MEMORY_SCOPE_AGENT) == 0) {}
                mm = *(const float2*)&mvb[t * 16 + 2 * wv];  // fresh post-inv
            } else {
                mm = mmn;  // prefetched (batch-validated)
            }
            int tn = (t + 1 < NS) ? t + 1 : NS - 1;
            mmn = *(const float2*)&mvb[tn * 16 + 2 * wv];

            float4 y0 = *(const float4*)&hs[p][4 * l];
            float4 y1 = *(const float4*)&hs[p][256 + 4 * l];
            float r5 = dot8(u22a, u22b, y0, y1);
            float r6 = dot8(du22a, du22b, y0, y1);
            r5 = dpp_sum64(r5); r6 = dpp_sum64(r6);
            float m5 = bcast63(r5), m6 = bcast63(r6);

            float g0 = cW2[0] * mm.x + cdW2[0] * mm.y + cU2[0] * m5 + cdU2[0] * m6 + bb2[0];
            float g1 = cW2[1] * mm.x + cdW2[1] * mm.y + cU2[1] * m5 + cdU2[1] * m6 + bb2[1];
            float g2 = cW2[2] * mm.x + cdW2[2] * mm.y + cU2[2] * m5 + cdU2[2] * m6 + bb2[2];
            float g3 = cW2[3] * mm.x + cdW2[3] * mm.y + cU2[3] * m5 + cdU2[3] * m6 + bb2[3];
            float ig = sigm(g0), fg = sigm(g1), gg = tanh_fast(g2), og = sigm(g3);
            c2 = fg * c2 + ig * gg;
            h2v = og * tanh_fast(c2);
            hs[p ^ 1][tid] = h2v;
            outb[(size_t)t * NH + h] = h2v;  // fire-and-forget
            wg_barrier();
        }
        hn[(size_t)NB * NH + (size_t)b * NH + h] = h2v;
        cn[(size_t)NB * NH + (size_t)b * NH + h] = c2;
    }
}

extern "C" void kernel_launch(void* const* d_in, const int* in_sizes, int n_in,
                              void* d_out, int out_size, void* d_ws, size_t ws_size,
                              hipStream_t stream) {
    const float* x = (const float*)d_in[0];
    const float* h0 = (const float*)d_in[1];
    const float* c0 = (const float*)d_in[2];
    const float* W11 = (const float*)d_in[3];
    const float* W12 = (const float*)d_in[4];
    const float* U11 = (const float*)d_in[5];
    const float* U12 = (const float*)d_in[6];
    const float* dW11 = (const float*)d_in[7];
    const float* dW12 = (const float*)d_in[8];
    const float* dU11 = (const float*)d_in[9];
    const float* dU12 = (const float*)d_in[10];
    const float* b11 = (const float*)d_in[11];
    const float* b12 = (const float*)d_in[12];
    const float* W21 = (const float*)d_in[13];
    const float* W22 = (const float*)d_in[14];
    const float* U21 = (const float*)d_in[15];
    const float* U22 = (const float*)d_in[16];
    const float* dW21 = (const float*)d_in[17];
    const float* dW22 = (const float*)d_in[18];
    const float* dU21 = (const float*)d_in[19];
    const float* dU22 = (const float*)d_in[20];
    const float* b21 = (const float*)d_in[21];
    const float* b22 = (const float*)d_in[22];

    char* ws = (char*)d_ws;
    float* P = (float*)ws;                                   // 2 MB
    float* mval = (float*)(ws + (size_t)NB * NS * 16 * 4);   // 2 MB
    unsigned int* flagb = (unsigned int*)(ws + 2 * (size_t)NB * NS * 16 * 4);  // 16 KB
    float* out = (float*)d_out;

    hipMemsetAsync(flagb, 0, NB * (NS / 8) * sizeof(unsigned int), stream);
    hipLaunchKernelGGL(precomp_kernel, dim3(NB * NS), dim3(64), 0, stream,
                       x, W12, dW12, P);
    hipLaunchKernelGGL(lstm_pipe_kernel, dim3(2 * NB), dim3(512), 0, stream,
                       P, h0, c0,
                       W11, U11, dW11, dU11, U12, dU12, b11, b12,
                       W21, U21, dW21, dU21, W22, dW22, U22, dU22, b21, b22,
                       mval, flagb, out);
}

// Round 8
// 503.446 us; speedup vs baseline: 2.1841x; 1.0929x over previous
//
#include <hip/hip_runtime.h>
#include <math.h>

#define NB 64       // batch
#define NS 512      // seq len
#define ND 512      // input dim
#define NH 512      // hidden
// F = 8 factor rows, G = 256

__device__ __forceinline__ float dot8(float4 a0, float4 a1, float4 x0, float4 x1) {
    float s = a0.x * x0.x;
    s = fmaf(a0.y, x0.y, s); s = fmaf(a0.z, x0.z, s); s = fmaf(a0.w, x0.w, s);
    s = fmaf(a1.x, x1.x, s); s = fmaf(a1.y, x1.y, s); s = fmaf(a1.z, x1.z, s);
    s = fmaf(a1.w, x1.w, s);
    return s;
}

// 64-lane sum via DPP (VALU only, no LDS). Total ends in lane 63.
__device__ __forceinline__ float dpp_sum64(float x) {
    x += __int_as_float(__builtin_amdgcn_update_dpp(0, __float_as_int(x), 0x111, 0xf, 0xf, true)); // row_shr:1
    x += __int_as_float(__builtin_amdgcn_update_dpp(0, __float_as_int(x), 0x112, 0xf, 0xf, true)); // row_shr:2
    x += __int_as_float(__builtin_amdgcn_update_dpp(0, __float_as_int(x), 0x114, 0xf, 0xf, true)); // row_shr:4
    x += __int_as_float(__builtin_amdgcn_update_dpp(0, __float_as_int(x), 0x118, 0xf, 0xf, true)); // row_shr:8
    x += __int_as_float(__builtin_amdgcn_update_dpp(0, __float_as_int(x), 0x142, 0xa, 0xf, true)); // row_bcast:15
    x += __int_as_float(__builtin_amdgcn_update_dpp(0, __float_as_int(x), 0x143, 0xc, 0xf, true)); // row_bcast:31
    return x;
}

__device__ __forceinline__ float bcast63(float x) {
    return __int_as_float(__builtin_amdgcn_readlane(__float_as_int(x), 63));
}

__device__ __forceinline__ float sigm(float x) {
    return 1.0f / (1.0f + __expf(-x));
}

__device__ __forceinline__ float tanh_fast(float x) {
    float ax = fabsf(x);
    float e = __expf(2.0f * ax);
    float r = 1.0f - 2.0f / (e + 1.0f);
    return copysignf(r, x);
}

// lgkm-only barrier: global stores stay in flight across steps.
__device__ __forceinline__ void wg_barrier() {
    asm volatile("s_waitcnt lgkmcnt(0)\n\ts_barrier" ::: "memory");
}
// full-drain barrier: all waves' VMEM ops retired before anyone passes.
__device__ __forceinline__ void full_barrier() {
    asm volatile("s_waitcnt vmcnt(0) lgkmcnt(0)\n\ts_barrier" ::: "memory");
}

// ---------------------------------------------------------------------------
// Kernel A: P[bt][2f] = (W12 @ x_bt)[f], P[bt][2f+1] = (dW12 @ x_bt)[f]
// ---------------------------------------------------------------------------
__global__ __launch_bounds__(64) void precomp_kernel(
    const float* __restrict__ x, const float* __restrict__ W12,
    const float* __restrict__ dW12, float* __restrict__ P) {
    int bt = blockIdx.x;
    int l = threadIdx.x;  // 0..63
    const float4* xr = (const float4*)(x + (size_t)bt * ND);
    float4 xv0 = xr[l];
    float4 xv1 = xr[64 + l];

    float acc[16];
#pragma unroll
    for (int f = 0; f < 8; ++f) {
        const float4* w = (const float4*)(W12 + f * ND);
        acc[f] = dot8(w[l], w[64 + l], xv0, xv1);
        const float4* dw = (const float4*)(dW12 + f * ND);
        acc[8 + f] = dot8(dw[l], dw[64 + l], xv0, xv1);
    }
#pragma unroll
    for (int f = 0; f < 16; ++f) acc[f] = dpp_sum64(acc[f]);

    if (l == 63) {
        float4* o = (float4*)(P + (size_t)bt * 16);
        o[0] = make_float4(acc[0], acc[8], acc[1], acc[9]);
        o[1] = make_float4(acc[2], acc[10], acc[3], acc[11]);
        o[2] = make_float4(acc[4], acc[12], acc[5], acc[13]);
        o[3] = make_float4(acc[6], acc[14], acc[7], acc[15]);
    }
}

// ---------------------------------------------------------------------------
// Kernel B: 2-stage pipeline, 2 blocks per batch element (128 blocks).
// role 0: layer-1 recurrence + W22/dW22 projections -> mvalT (chunk layout)
// role 1: layer-2 recurrence, 8-step chunks: ONE acquire + ONE batched
//         wave-uniform m-load per chunk; zero VMEM waits inside the chunk.
//         Natural LDS layout so out[t-1] stores are coalesced float4 from
//         the y-registers (deferred), drained only at chunk boundaries.
// ---------------------------------------------------------------------------
__global__ __launch_bounds__(512) void lstm_pipe_kernel(
    const float* __restrict__ P, const float* __restrict__ h0,
    const float* __restrict__ c0,
    const float* __restrict__ W11, const float* __restrict__ U11,
    const float* __restrict__ dW11, const float* __restrict__ dU11,
    const float* __restrict__ U12, const float* __restrict__ dU12,
    const float* __restrict__ b11, const float* __restrict__ b12,
    const float* __restrict__ W21, const float* __restrict__ U21,
    const float* __restrict__ dW21, const float* __restrict__ dU21,
    const float* __restrict__ W22, const float* __restrict__ dW22,
    const float* __restrict__ U22, const float* __restrict__ dU22,
    const float* __restrict__ b21, const float* __restrict__ b22,
    float* __restrict__ mvalT, unsigned int* __restrict__ flagb,
    float* __restrict__ out) {
    int role = blockIdx.x >> 6;   // 0 = producer (L1), 1 = consumer (L2)
    int b = blockIdx.x & 63;
    int tid = threadIdx.x;
    int wv = tid >> 6;            // wave = factor row
    int l = tid & 63;             // lane
    int h = 8 * l + wv;           // owned hidden row

    __shared__ float Ps[NS * 16];   // 32 KB (producer only)
    __shared__ float hs[2][NH];     // 4 KB state double-buffer

    float* hn = out + (size_t)NB * NS * NH;
    float* cn = hn + (size_t)2 * NB * NH;

    if (role == 0) {
        // =================== PRODUCER: layer 1 ===================
        {
            const float4* src = (const float4*)(P + (size_t)b * NS * 16);
            float4* dst = (float4*)Ps;
#pragma unroll
            for (int i = 0; i < 4; ++i) dst[tid + i * 512] = src[tid + i * 512];
        }
        // permuted weight gather (LDS slot tid = row 8*(tid&63)+(tid>>6))
        int kb = 32 * (l & 15) + (l >> 4);
        float4 u12a, u12b, du12a, du12b, w22a, w22b, dw22a, dw22b;
        {
            const float* M;
#define LOADWP(mat, ra, rb)                                             \
            M = (mat) + wv * NH;                                        \
            ra = make_float4(M[kb], M[kb + 8], M[kb + 16], M[kb + 24]); \
            rb = make_float4(M[kb + 4], M[kb + 12], M[kb + 20], M[kb + 28]);
            LOADWP(U12, u12a, u12b)
            LOADWP(dU12, du12a, du12b)
            LOADWP(W22, w22a, w22b)
            LOADWP(dW22, dw22a, dw22b)
#undef LOADWP
        }
        float cW1[4], cdW1[4], cU1[4], cdU1[4], bb1[4];
#pragma unroll
        for (int q = 0; q < 4; ++q) {
            int idx = q * 64 + l;
            cW1[q] = W11[idx]; cdW1[q] = dW11[idx];
            cU1[q] = U11[idx]; cdU1[q] = dU11[idx];
            bb1[q] = b11[q * NH + h] + b12[q * NH + h];
        }
        float c1 = c0[(size_t)b * NH + h];
        float h1v = h0[(size_t)b * NH + h];
        hs[0][tid] = h1v;   // permuted slot tid = own row
        wg_barrier();

        // prologue: h1(1) from h1(0), x(0)
        {
            float2 pp = *(const float2*)&Ps[2 * wv];
            float4 x0 = *(const float4*)&hs[0][4 * l];
            float4 x1 = *(const float4*)&hs[0][256 + 4 * l];
            float r3 = dot8(u12a, u12b, x0, x1);
            float r4 = dot8(du12a, du12b, x0, x1);
            float m3 = bcast63(dpp_sum64(r3));
            float m4 = bcast63(dpp_sum64(r4));
            wg_barrier();
            float g0 = cW1[0] * pp.x + cdW1[0] * pp.y + cU1[0] * m3 + cdU1[0] * m4 + bb1[0];
            float g1 = cW1[1] * pp.x + cdW1[1] * pp.y + cU1[1] * m3 + cdU1[1] * m4 + bb1[1];
            float g2 = cW1[2] * pp.x + cdW1[2] * pp.y + cU1[2] * m3 + cdU1[2] * m4 + bb1[2];
            float g3 = cW1[3] * pp.x + cdW1[3] * pp.y + cU1[3] * m3 + cdU1[3] * m4 + bb1[3];
            float ig = sigm(g0), fg = sigm(g1), gg = tanh_fast(g2), og = sigm(g3);
            c1 = fg * c1 + ig * gg;
            h1v = og * tanh_fast(c1);
            hs[0][tid] = h1v;
            wg_barrier();
        }
        float p1, p2;
        {
            float2 pp = *(const float2*)&Ps[16 + 2 * wv];
            p1 = pp.x; p2 = pp.y;
        }
        unsigned int* fbb = flagb + b * (NS / 8);

        for (int t = 0; t < NS; ++t) {
            if ((t & 7) == 0 && t > 0 && tid == 0)
                __hip_atomic_store(&fbb[(t >> 3) - 1], 1u,
                                   __ATOMIC_RELEASE, __HIP_MEMORY_SCOPE_AGENT);
            const int p = t & 1;
            int tn = (t + 2 < NS) ? t + 2 : NS - 1;
            float2 ppn = *(const float2*)&Ps[tn * 16 + 2 * wv];

            float4 x0 = *(const float4*)&hs[p][4 * l];
            float4 x1 = *(const float4*)&hs[p][256 + 4 * l];
            float r1 = dot8(w22a, w22b, x0, x1);
            float r2 = dot8(dw22a, dw22b, x0, x1);
            float r3 = dot8(u12a, u12b, x0, x1);
            float r4 = dot8(du12a, du12b, x0, x1);
            r1 = dpp_sum64(r1); r2 = dpp_sum64(r2);
            r3 = dpp_sum64(r3); r4 = dpp_sum64(r4);
            float m1 = bcast63(r1), m2 = bcast63(r2);
            float m3 = bcast63(r3), m4 = bcast63(r4);
            // chunk-transposed record: [b][t>>3][wv][t&7][2]
            if (l == 63) {
                float* rec = mvalT + (((size_t)(b * (NS / 8) + (t >> 3))) * 8 + wv) * 16;
                *(float2*)&rec[(t & 7) * 2] = make_float2(m1, m2);
            }

            if (t < NS - 1) {
                float g0 = cW1[0] * p1 + cdW1[0] * p2 + cU1[0] * m3 + cdU1[0] * m4 + bb1[0];
                float g1 = cW1[1] * p1 + cdW1[1] * p2 + cU1[1] * m3 + cdU1[1] * m4 + bb1[1];
                float g2 = cW1[2] * p1 + cdW1[2] * p2 + cU1[2] * m3 + cdU1[2] * m4 + bb1[2];
                float g3 = cW1[3] * p1 + cdW1[3] * p2 + cU1[3] * m3 + cdU1[3] * m4 + bb1[3];
                float ig = sigm(g0), fg = sigm(g1), gg = tanh_fast(g2), og = sigm(g3);
                c1 = fg * c1 + ig * gg;
                h1v = og * tanh_fast(c1);
                hs[p ^ 1][tid] = h1v;
            }
            p1 = ppn.x; p2 = ppn.y;
            if ((t & 7) == 7) full_barrier(); else wg_barrier();
        }
        if (tid == 0)
            __hip_atomic_store(&fbb[(NS / 8) - 1], 1u,
                               __ATOMIC_RELEASE, __HIP_MEMORY_SCOPE_AGENT);
        hn[(size_t)b * NH + h] = h1v;
        cn[(size_t)b * NH + h] = c1;
    } else {
        // =================== CONSUMER: layer 2 ===================
        // NATURAL layout: LDS slot s = row s. Weight gather is plain float4.
        float4 u22a, u22b, du22a, du22b;
        {
            const float4* pU22 = (const float4*)(U22 + wv * NH);
            const float4* pdU22 = (const float4*)(dU22 + wv * NH);
            u22a = pU22[l]; u22b = pU22[64 + l];
            du22a = pdU22[l]; du22b = pdU22[64 + l];
        }
        float cW2[4], cdW2[4], cU2[4], cdU2[4], bb2[4];
#pragma unroll
        for (int q = 0; q < 4; ++q) {
            int idx = q * 64 + l;
            cW2[q] = W21[idx]; cdW2[q] = dW21[idx];
            cU2[q] = U21[idx]; cdU2[q] = dU21[idx];
            bb2[q] = b21[q * NH + h] + b22[q * NH + h];
        }
        float c2 = c0[(size_t)NB * NH + (size_t)b * NH + h];
        float h2v = h0[(size_t)NB * NH + (size_t)b * NH + h];
        hs[0][tid] = h0[(size_t)NB * NH + (size_t)b * NH + tid];  // natural
        wg_barrier();

        const unsigned int* fbb = flagb + b * (NS / 8);
        float* outb = out + (size_t)b * NS * NH;

        for (int c = 0; c < NS / 8; ++c) {
            // one acquire per chunk; then ONE batched wave-uniform m-load
            while (__hip_atomic_load(&fbb[c], __ATOMIC_ACQUIRE,
                                     __HIP_MEMORY_SCOPE_AGENT) == 0) {}
            const float4* rec = (const float4*)(mvalT +
                (((size_t)(b * (NS / 8) + c)) * 8 + wv) * 16);
            float4 q0 = rec[0], q1 = rec[1], q2 = rec[2], q3 = rec[3];
            float mq[16] = {q0.x, q0.y, q0.z, q0.w, q1.x, q1.y, q1.z, q1.w,
                            q2.x, q2.y, q2.z, q2.w, q3.x, q3.y, q3.z, q3.w};

#pragma unroll
            for (int j = 0; j < 8; ++j) {
                int t = c * 8 + j;
                const int p = t & 1;
                float4 y0 = *(const float4*)&hs[p][4 * l];
                float4 y1 = *(const float4*)&hs[p][256 + 4 * l];

                // deferred coalesced store: y = h2(t) = out[t-1] (natural rows)
                if (t > 0 && wv == 0)
                    *(float4*)&outb[(size_t)(t - 1) * NH + 4 * l] = y0;
                if (t > 0 && wv == 1)
                    *(float4*)&outb[(size_t)(t - 1) * NH + 256 + 4 * l] = y1;

                float r5 = dot8(u22a, u22b, y0, y1);
                float r6 = dot8(du22a, du22b, y0, y1);
                r5 = dpp_sum64(r5); r6 = dpp_sum64(r6);
                float m5 = bcast63(r5), m6 = bcast63(r6);
                float mx = mq[2 * j], my = mq[2 * j + 1];  // static idx

                float g0 = cW2[0] * mx + cdW2[0] * my + cU2[0] * m5 + cdU2[0] * m6 + bb2[0];
                float g1 = cW2[1] * mx + cdW2[1] * my + cU2[1] * m5 + cdU2[1] * m6 + bb2[1];
                float g2 = cW2[2] * mx + cdW2[2] * my + cU2[2] * m5 + cdU2[2] * m6 + bb2[2];
                float g3 = cW2[3] * mx + cdW2[3] * my + cU2[3] * m5 + cdU2[3] * m6 + bb2[3];
                float ig = sigm(g0), fg = sigm(g1), gg = tanh_fast(g2), og = sigm(g3);
                c2 = fg * c2 + ig * gg;
                h2v = og * tanh_fast(c2);
                hs[p ^ 1][h] = h2v;  // scattered ds_write (natural layout)
                wg_barrier();
            }
        }
        // out[NS-1] = h2(NS), held in hs[((NS-1)&1)^1] = hs[0] (natural)
        outb[(size_t)(NS - 1) * NH + tid] = hs[0][tid];
        hn[(size_t)NB * NH + (size_t)b * NH + h] = h2v;
        cn[(size_t)NB * NH + (size_t)b * NH + h] = c2;
    }
}

extern "C" void kernel_launch(void* const* d_in, const int* in_sizes, int n_in,
                              void* d_out, int out_size, void* d_ws, size_t ws_size,
                              hipStream_t stream) {
    const float* x = (const float*)d_in[0];
    const float* h0 = (const float*)d_in[1];
    const float* c0 = (const float*)d_in[2];
    const float* W11 = (const float*)d_in[3];
    const float* W12 = (const float*)d_in[4];
    const float* U11 = (const float*)d_in[5];
    const float* U12 = (const float*)d_in[6];
    const float* dW11 = (const float*)d_in[7];
    const float* dW12 = (const float*)d_in[8];
    const float* dU11 = (const float*)d_in[9];
    const float* dU12 = (const float*)d_in[10];
    const float* b11 = (const float*)d_in[11];
    const float* b12 = (const float*)d_in[12];
    const float* W21 = (const float*)d_in[13];
    const float* W22 = (const float*)d_in[14];
    const float* U21 = (const float*)d_in[15];
    const float* U22 = (const float*)d_in[16];
    const float* dW21 = (const float*)d_in[17];
    const float* dW22 = (const float*)d_in[18];
    const float* dU21 = (const float*)d_in[19];
    const float* dU22 = (const float*)d_in[20];
    const float* b21 = (const float*)d_in[21];
    const float* b22 = (const float*)d_in[22];

    char* ws = (char*)d_ws;
    float* P = (float*)ws;                                   // 2 MB
    float* mvalT = (float*)(ws + (size_t)NB * NS * 16 * 4);  // 2 MB
    unsigned int* flagb = (unsigned int*)(ws + 2 * (size_t)NB * NS * 16 * 4);  // 16 KB
    float* out = (float*)d_out;

    hipMemsetAsync(flagb, 0, NB * (NS / 8) * sizeof(unsigned int), stream);
    hipLaunchKernelGGL(precomp_kernel, dim3(NB * NS), dim3(64), 0, stream,
                       x, W12, dW12, P);
    hipLaunchKernelGGL(lstm_pipe_kernel, dim3(2 * NB), dim3(512), 0, stream,
                       P, h0, c0,
                       W11, U11, dW11, dU11, U12, dU12, b11, b12,
                       W21, U21, dW21, dU21, W22, dW22, U22, dU22, b21, b22,
                       mvalT, flagb, out);
}